// Round 7
// baseline (788.779 us; speedup 1.0000x reference)
//
#include <hip/hip_runtime.h>

#define B 2
#define S 2048
#define D 768
#define H 12
#define DH 64
#define TOPK 512
#define NROW (B*S)   // 4096

typedef __attribute__((ext_vector_type(8))) short bf16x8;
typedef __attribute__((ext_vector_type(8))) ushort u16x8;
typedef __attribute__((ext_vector_type(4))) float f32x4;

// ---- bf16 split helpers (hi = RNE bf16 of x, lo = RNE bf16 of residual) ----
__device__ __forceinline__ ushort bf16_hi(float x) {
  union { float f; unsigned u; } v; v.f = x;
  unsigned r = v.u + 0x7fffu + ((v.u >> 16) & 1u);
  return (ushort)(r >> 16);
}
__device__ __forceinline__ float bf16_tof(ushort h) {
  union { float f; unsigned u; } v; v.u = ((unsigned)h) << 16; return v.f;
}
__device__ __forceinline__ void bf16_split(float x, ushort& h, ushort& l) {
  h = bf16_hi(x);
  l = bf16_hi(x - bf16_tof(h));
}

// ---------------------------------------------------------------------------
// Split fp32 tensor -> bf16 hi/lo buffers. 8 elements/thread.
// ---------------------------------------------------------------------------
__global__ __launch_bounds__(256) void split_kernel(
    const float* __restrict__ src, ushort* __restrict__ dh,
    ushort* __restrict__ dl, int n8) {
  int i = blockIdx.x*256 + threadIdx.x;
  if (i >= n8) return;
  float v[8];
  *(float4*)&v[0] = ((const float4*)src)[i*2];
  *(float4*)&v[4] = ((const float4*)src)[i*2+1];
  ushort hh[8], ll[8];
#pragma unroll
  for (int k = 0; k < 8; ++k) bf16_split(v[k], hh[k], ll[k]);
  ((u16x8*)dh)[i] = *(u16x8*)&hh[0];
  ((u16x8*)dl)[i] = *(u16x8*)&ll[0];
}

// ---------------------------------------------------------------------------
// Fused 4-way weight split (z = 0..3 selects Wq/Wk/Wv/Wo). Dst pairs are
// contiguous in ws: base + z*2*WSZ (hi), + WSZ (lo). Same math as split_kernel.
// ---------------------------------------------------------------------------
__global__ __launch_bounds__(256) void splitw4_kernel(
    const float* __restrict__ w0, const float* __restrict__ w1,
    const float* __restrict__ w2, const float* __restrict__ w3,
    ushort* __restrict__ dbase, int n8) {
  int z = blockIdx.z;
  const float* src = (z == 0) ? w0 : (z == 1) ? w1 : (z == 2) ? w2 : w3;
  ushort* dh = dbase + (size_t)z * 2u * (size_t)(D*D);
  ushort* dl = dh + (size_t)(D*D);
  int i = blockIdx.x*256 + threadIdx.x;
  if (i >= n8) return;
  float v[8];
  *(float4*)&v[0] = ((const float4*)src)[i*2];
  *(float4*)&v[4] = ((const float4*)src)[i*2+1];
  ushort hh[8], ll[8];
#pragma unroll
  for (int k = 0; k < 8; ++k) bf16_split(v[k], hh[k], ll[k]);
  ((u16x8*)dh)[i] = *(u16x8*)&hh[0];
  ((u16x8*)dl)[i] = *(u16x8*)&ll[0];
}

// ---------------------------------------------------------------------------
// Split-bf16 MFMA GEMM: C = A (N x 768) @ W^T + bias, * scale
// Block 256 = 4 waves, tile 64x64, wave tile 32x32 (2x2 fragments).
// MODE 0: C row-major [N][768] fp32; MODE 1: C scattered to [b][h][s][dh]
// ---------------------------------------------------------------------------
template<int MODE>
__global__ __launch_bounds__(256) void projmf_kernel(
    const ushort* __restrict__ Ah, const ushort* __restrict__ Al,
    const ushort* __restrict__ Wh, const ushort* __restrict__ Wl,
    const float* __restrict__ bias, float* __restrict__ C, float scale) {
  int tid = threadIdx.x;
  int w = tid >> 6, lane = tid & 63;
  int lr = lane & 15, lg = lane >> 4;
  int n0 = blockIdx.x*64 + (w >> 1)*32;
  int m0 = blockIdx.y*64 + (w & 1)*32;
  f32x4 acc[2][2] = {};
  for (int ks = 0; ks < 24; ++ks) {
    int ko = ks*32 + lg*8;
    bf16x8 ah[2], al[2], wh[2], wl[2];
#pragma unroll
    for (int i = 0; i < 2; ++i) {
      size_t ao = (size_t)(n0 + 16*i + lr)*768 + ko;
      ah[i] = *(const bf16x8*)(Ah + ao);
      al[i] = *(const bf16x8*)(Al + ao);
      size_t wo = (size_t)(m0 + 16*i + lr)*768 + ko;
      wh[i] = *(const bf16x8*)(Wh + wo);
      wl[i] = *(const bf16x8*)(Wl + wo);
    }
#pragma unroll
    for (int i = 0; i < 2; ++i)
#pragma unroll
      for (int j = 0; j < 2; ++j) {
        acc[i][j] = __builtin_amdgcn_mfma_f32_16x16x32_bf16(ah[i], wh[j], acc[i][j], 0, 0, 0);
        acc[i][j] = __builtin_amdgcn_mfma_f32_16x16x32_bf16(ah[i], wl[j], acc[i][j], 0, 0, 0);
        acc[i][j] = __builtin_amdgcn_mfma_f32_16x16x32_bf16(al[i], wh[j], acc[i][j], 0, 0, 0);
        acc[i][j] = __builtin_amdgcn_mfma_f32_16x16x32_bf16(al[i], wl[j], acc[i][j], 0, 0, 0);
      }
  }
#pragma unroll
  for (int i = 0; i < 2; ++i)
#pragma unroll
    for (int j = 0; j < 2; ++j) {
      int m = m0 + 16*j + lr;
      float bv = bias[m];
#pragma unroll
      for (int r = 0; r < 4; ++r) {
        int n = n0 + 16*i + lg*4 + r;
        float val = (acc[i][j][r] + bv) * scale;
        if (MODE == 0) {
          C[(size_t)n*D + m] = val;
        } else {
          int b = n >> 11, s = n & 2047, hh = m >> 6, dh = m & 63;
          C[(((size_t)b*H + hh)*S + s)*DH + dh] = val;
        }
      }
    }
}

// ---------------------------------------------------------------------------
// Leverage stage A1: per-head partial KtK over 128-row chunks (batch 0 only)
// ---------------------------------------------------------------------------
__global__ __launch_bounds__(256) void levA1_kernel(
    const float* __restrict__ Kmat, float* __restrict__ partials) {
  int h = blockIdx.x, blk = blockIdx.y;
  __shared__ __align__(16) float ktile[128*64];
  int tid = threadIdx.x;
  const float* Kh = Kmat + ((size_t)h*S + (size_t)blk*128)*DH;
#pragma unroll
  for (int r = 0; r < 32; ++r) { int e = tid + 256*r; ktile[e] = Kh[e]; }
  __syncthreads();
  int j4 = tid & 15;
  float accf[4][4] = {};
  for (int ss = 0; ss < 128; ++ss) {
    float4 kj = ((const float4*)(ktile + ss*64))[j4];
#pragma unroll
    for (int r = 0; r < 4; ++r) {
      int i = (tid >> 4) + 16*r;
      float ki = ktile[ss*64 + i];
      accf[r][0] += ki*kj.x; accf[r][1] += ki*kj.y;
      accf[r][2] += ki*kj.z; accf[r][3] += ki*kj.w;
    }
  }
  size_t base = ((size_t)h*16 + blk)*4096;
#pragma unroll
  for (int r = 0; r < 4; ++r) {
    int i = (tid >> 4) + 16*r;
#pragma unroll
    for (int c = 0; c < 4; ++c)
      partials[base + (size_t)i*64 + j4*4 + c] = accf[r][c];
  }
}

// ---------------------------------------------------------------------------
// Leverage stage A0-reduce: wide parallel fp64 sum of the 16 partials
// (same p=0..15 order -> bitwise-identical KtK) + damping.
// ---------------------------------------------------------------------------
__global__ __launch_bounds__(256) void levA0_kernel(
    const float* __restrict__ partials, float* __restrict__ KtK) {
  int g = blockIdx.x*256 + threadIdx.x;        // 0 .. H*4096-1
  int h = g >> 12, e = g & 4095;
  const float* pb = partials + (size_t)h*65536 + e;
  double t = 0.0;
#pragma unroll
  for (int p = 0; p < 16; ++p) t += (double)pb[(size_t)p*4096];
  if ((e >> 6) == (e & 63)) t += 1e-6;
  KtK[g] = (float)t;
}

// ---------------------------------------------------------------------------
// Leverage stage A2 (v4): R5's LDS Gauss-Jordan, phase-split.
// One block (256 thr) per head; thread (r = tid&63, q = tid>>6) owns cols
// [q*32, q*32+32) of augmented row r. aug stride 131 (odd -> 2-way bank
// aliasing = free; wave = quarter -> the R5 lockstep property).
// Per pivot: READ phase (f, piv, pivot-row chunk, own chunk -> registers),
// barrier, WRITE phase (n = pv*ipiv redundant-normalize; fma(-f,n,own)),
// barrier. Values read are the same pre-update state R5 read -> the inverse
// is BITWISE R5's (absmax canary: 1.220703e-3). Distinct read/write windows
// -> provably race-free; batched reads pipeline (no per-column LDS chain).
// ---------------------------------------------------------------------------
__global__ __launch_bounds__(256) void levA2_kernel(
    const float* __restrict__ KtK, float* __restrict__ invOut) {
  __shared__ float A_[64*131 + 1];
  int h = blockIdx.x, tid = threadIdx.x;
  int r = tid & 63, q = tid >> 6;
  int c0 = q * 32;
  // init: cols 0..63 = KtK (damped), cols 64..127 = I  (same as R5)
  float* row = A_ + r*131;
  const float* src = KtK + (size_t)h*4096 + r*64;
#pragma unroll
  for (int i = 0; i < 32; ++i) {
    int c = c0 + i;
    row[c] = (c < 64) ? src[c] : ((c - 64 == r) ? 1.0f : 0.0f);
  }
  __syncthreads();
  for (int p = 0; p < 64; ++p) {
    // ---- read phase: everything into registers, pre-update state ----
    float f = row[p];                  // own row's old col-p value
    float piv = A_[p*131 + p];         // A[p][p]
    float ipiv = 1.0f / piv;
    bool isp = (r == p);
    const float* prow = A_ + p*131;
    float2 pv[16], ov[16];
#pragma unroll
    for (int i = 0; i < 16; ++i) {
      pv[i] = *(const float2*)&prow[c0 + 2*i];   // broadcast within wave
      ov[i] = *(const float2*)&row[c0 + 2*i];
    }
    __syncthreads();
    // ---- write phase: identical per-element arithmetic to R5 ----
#pragma unroll
    for (int i = 0; i < 16; ++i) {
      float n0 = pv[i].x * ipiv, n1 = pv[i].y * ipiv;
      float o0 = isp ? n0 : fmaf(-f, n0, ov[i].x);
      float o1 = isp ? n1 : fmaf(-f, n1, ov[i].y);
      *(float2*)&row[c0 + 2*i] = make_float2(o0, o1);
    }
    __syncthreads();
  }
  // extract inverse (cols 64..127), same as R5
  size_t obase = (size_t)h*4096 + (size_t)tid*16;
#pragma unroll
  for (int i = 0; i < 16; ++i) {
    int e = tid*16 + i;
    invOut[obase + i] = A_[(e >> 6)*131 + 64 + (e & 63)];
  }
}

// ---------------------------------------------------------------------------
// Leverage stage B: lev[h][s] = k_s^T inv_h k_s
// ---------------------------------------------------------------------------
__global__ __launch_bounds__(256) void levB_kernel(
    const float* __restrict__ Kmat, const float* __restrict__ invMat,
    float* __restrict__ lev) {
  int h = blockIdx.x;
  int s = blockIdx.y*256 + threadIdx.x;
  __shared__ __align__(16) float inv[64*64];
#pragma unroll
  for (int r = 0; r < 16; ++r)
    inv[threadIdx.x + 256*r] = invMat[(size_t)h*4096 + threadIdx.x + 256*r];
  __syncthreads();
  float kv[64];
  const float* kr = Kmat + ((size_t)h*S + s)*DH;
#pragma unroll
  for (int d4 = 0; d4 < 16; ++d4) {
    float4 t = ((const float4*)kr)[d4];
    kv[4*d4+0]=t.x; kv[4*d4+1]=t.y; kv[4*d4+2]=t.z; kv[4*d4+3]=t.w;
  }
  float acc = 0.f;
  for (int i = 0; i < 64; ++i) {
    float ti = 0.f;
    const float4* ir = (const float4*)(inv + i*64);
#pragma unroll
    for (int j4 = 0; j4 < 16; ++j4) {
      float4 iv = ir[j4];
      ti += iv.x*kv[4*j4] + iv.y*kv[4*j4+1] + iv.z*kv[4*j4+2] + iv.w*kv[4*j4+3];
    }
    acc += ti * kv[i];
  }
  lev[(size_t)h*S + s] = acc;
}

// ---------------------------------------------------------------------------
// Top-k via bitonic sort (value desc, index asc)
// ---------------------------------------------------------------------------
__global__ __launch_bounds__(256) void topk_kernel(
    const float* __restrict__ lev, int* __restrict__ idx_list) {
  int h = blockIdx.x, tid = threadIdx.x;
  __shared__ float sv[2048];
  __shared__ int   si[2048];
#pragma unroll
  for (int r = 0; r < 8; ++r) {
    int e = tid + 256*r;
    sv[e] = lev[(size_t)h*S + e];
    si[e] = e;
  }
  __syncthreads();
  for (int k = 2; k <= 2048; k <<= 1) {
    for (int j = k >> 1; j > 0; j >>= 1) {
      for (int r = 0; r < 8; ++r) {
        int i = tid + 256*r;
        int l = i ^ j;
        if (l > i) {
          float v1 = sv[i], v2 = sv[l];
          int   i1 = si[i], i2 = si[l];
          bool before = (v1 > v2) || (v1 == v2 && i1 < i2);
          bool dir = ((i & k) == 0);
          if (before != dir) { sv[i]=v2; sv[l]=v1; si[i]=i2; si[l]=i1; }
        }
      }
      __syncthreads();
    }
  }
#pragma unroll
  for (int r = 0; r < 2; ++r) {
    int t = tid + 256*r;
    idx_list[h*TOPK + t] = si[t];
  }
}

// ---------------------------------------------------------------------------
// Gather kept K/V rows -> bf16 split buffers.
// KCh/KCl: [bh][512][64]; VCth/VCtl: [bh][64][512] (transposed)
// ---------------------------------------------------------------------------
__global__ __launch_bounds__(256) void gather_kernel(
    const float* __restrict__ Kmat, const float* __restrict__ Vmat,
    const int* __restrict__ idx_list,
    ushort* __restrict__ KCh, ushort* __restrict__ KCl,
    ushort* __restrict__ VCth, ushort* __restrict__ VCtl) {
  int bh = blockIdx.x;        // 0..23
  int kc = blockIdx.y;        // 0..7
  int h = bh % H;
  __shared__ float vt[64][65];
  int tid = threadIdx.x;
  int kk = tid >> 2;           // key within chunk (0..63)
  int dq = (tid & 3) * 16;     // dh base (0,16,32,48)
  int j = kc*64 + kk;
  int srow = idx_list[h*TOPK + j];
  const float* kr = Kmat + ((size_t)bh*S + srow)*DH + dq;
  const float* vr = Vmat + ((size_t)bh*S + srow)*DH + dq;
  ushort hh[16], ll[16];
#pragma unroll
  for (int i = 0; i < 16; ++i) bf16_split(kr[i], hh[i], ll[i]);
  size_t kbase = ((size_t)bh*TOPK + j)*DH + dq;
  *(u16x8*)(KCh + kbase)     = *(u16x8*)&hh[0];
  *(u16x8*)(KCh + kbase + 8) = *(u16x8*)&hh[8];
  *(u16x8*)(KCl + kbase)     = *(u16x8*)&ll[0];
  *(u16x8*)(KCl + kbase + 8) = *(u16x8*)&ll[8];
#pragma unroll
  for (int i = 0; i < 16; ++i) vt[kk][dq + i] = vr[i];
  __syncthreads();
  int d  = tid >> 2;           // dh row (0..63)
  int kq = (tid & 3) * 16;     // key base within chunk
#pragma unroll
  for (int i = 0; i < 16; ++i) bf16_split(vt[kq + i][d], hh[i], ll[i]);
  size_t vbase = ((size_t)bh*DH + d)*TOPK + kc*64 + kq;
  *(u16x8*)(VCth + vbase)     = *(u16x8*)&hh[0];
  *(u16x8*)(VCth + vbase + 8) = *(u16x8*)&hh[8];
  *(u16x8*)(VCtl + vbase)     = *(u16x8*)&ll[0];
  *(u16x8*)(VCtl + vbase + 8) = *(u16x8*)&ll[8];
}

// ---------------------------------------------------------------------------
// MFMA attention, split-bf16: single pass, 4 waves/block, wave-private LDS.
// Epilogue writes CTX as bf16 hi/lo (feeds the MFMA output projection).
// ---------------------------------------------------------------------------
__global__ __launch_bounds__(256) void attn_kernel(
    const float* __restrict__ Q,
    const ushort* __restrict__ KCh, const ushort* __restrict__ KCl,
    const ushort* __restrict__ VCth, const ushort* __restrict__ VCtl,
    ushort* __restrict__ CTXh, ushort* __restrict__ CTXl) {
  __shared__ __align__(16) ushort SQh[4][16][88];
  __shared__ __align__(16) ushort SQl[4][16][88];
  int tid = threadIdx.x;
  int w = tid >> 6;
  int lane = tid & 63;
  int lr = lane & 15, lg = lane >> 4;
  int bh = blockIdx.x >> 5;
  int qt = blockIdx.x & 31;
  int qbase = qt*64 + w*16;
  int b = bh / H, h = bh % H;

  bf16x8 qh[2], ql[2];
#pragma unroll
  for (int ks = 0; ks < 2; ++ks) {
    const float* qp = Q + ((size_t)bh*S + qbase + lr)*DH + ks*32 + lg*8;
    float qv[8];
    *(float4*)&qv[0] = *(const float4*)qp;
    *(float4*)&qv[4] = *(const float4*)(qp + 4);
#pragma unroll
    for (int i = 0; i < 8; ++i) {
      ushort hh, lo; bf16_split(qv[i], hh, lo);
      qh[ks][i] = (short)hh; ql[ks][i] = (short)lo;
    }
  }

  f32x4 pacc[4] = {};
  float z_acc[4] = {};

  for (int c = 0; c < 8; ++c) {
    int keybase = c*64;
    f32x4 sacc[4] = {};
#pragma unroll
    for (int ks = 0; ks < 2; ++ks) {
#pragma unroll
      for (int f = 0; f < 4; ++f) {
        size_t koff = ((size_t)bh*TOPK + keybase + 16*f + lr)*DH + ks*32 + lg*8;
        bf16x8 kh = *(const bf16x8*)(KCh + koff);
        bf16x8 kl = *(const bf16x8*)(KCl + koff);
        sacc[f] = __builtin_amdgcn_mfma_f32_16x16x32_bf16(qh[ks], kh, sacc[f], 0, 0, 0);
        sacc[f] = __builtin_amdgcn_mfma_f32_16x16x32_bf16(qh[ks], kl, sacc[f], 0, 0, 0);
        sacc[f] = __builtin_amdgcn_mfma_f32_16x16x32_bf16(ql[ks], kh, sacc[f], 0, 0, 0);
      }
    }
    float zc[4] = {};
#pragma unroll
    for (int f = 0; f < 4; ++f) {
#pragma unroll
      for (int r = 0; r < 4; ++r) {
        float s = sacc[f][r];
        float sq = s*s;
        zc[r] += sq;
        ushort hh, lo; bf16_split(sq, hh, lo);
        SQh[w][lg*4 + r][16*f + lr] = hh;
        SQl[w][lg*4 + r][16*f + lr] = lo;
      }
    }
#pragma unroll
    for (int r = 0; r < 4; ++r) {
      float t = zc[r];
      t += __shfl_xor(t, 1);
      t += __shfl_xor(t, 2);
      t += __shfl_xor(t, 4);
      t += __shfl_xor(t, 8);
      z_acc[r] += t;
    }
#pragma unroll
    for (int ks = 0; ks < 2; ++ks) {
      bf16x8 ah = *(const bf16x8*)&SQh[w][lr][ks*32 + lg*8];
      bf16x8 al = *(const bf16x8*)&SQl[w][lr][ks*32 + lg*8];
#pragma unroll
      for (int f = 0; f < 4; ++f) {
        size_t voff = ((size_t)bh*DH + 16*f + lr)*TOPK + keybase + ks*32 + lg*8;
        bf16x8 vh = *(const bf16x8*)(VCth + voff);
        bf16x8 vl = *(const bf16x8*)(VCtl + voff);
        pacc[f] = __builtin_amdgcn_mfma_f32_16x16x32_bf16(ah, vh, pacc[f], 0, 0, 0);
        pacc[f] = __builtin_amdgcn_mfma_f32_16x16x32_bf16(ah, vl, pacc[f], 0, 0, 0);
        pacc[f] = __builtin_amdgcn_mfma_f32_16x16x32_bf16(al, vh, pacc[f], 0, 0, 0);
      }
    }
  }

  float zi[4];
#pragma unroll
  for (int r = 0; r < 4; ++r) zi[r] = 1.0f / (z_acc[r] + 1e-12f);
#pragma unroll
  for (int f = 0; f < 4; ++f) {
#pragma unroll
    for (int r = 0; r < 4; ++r) {
      int q = lg*4 + r;
      float val = pacc[f][r] * zi[r];
      ushort hh, lo; bf16_split(val, hh, lo);
      size_t o = ((size_t)b*S + qbase + q)*D + h*DH + 16*f + lr;
      CTXh[o] = hh; CTXl[o] = lo;
    }
  }
}

// ---------------------------------------------------------------------------
extern "C" void kernel_launch(void* const* d_in, const int* in_sizes, int n_in,
                              void* d_out, int out_size, void* d_ws, size_t ws_size,
                              hipStream_t stream) {
  const float* query = (const float*)d_in[0];
  const float* key   = (const float*)d_in[1];
  const float* value = (const float*)d_in[2];
  const float* Wq = (const float*)d_in[3];
  const float* bq = (const float*)d_in[4];
  const float* Wk = (const float*)d_in[5];
  const float* bk = (const float*)d_in[6];
  const float* Wv = (const float*)d_in[7];
  const float* bv = (const float*)d_in[8];
  const float* Wo = (const float*)d_in[9];
  const float* bo = (const float*)d_in[10];
  float* out = (float*)d_out;

  float* ws = (float*)d_ws;
  const size_t QKV = (size_t)B*H*S*DH;        // 3,145,728
  const size_t WSZ = (size_t)D*D;             // 589,824
  float* Qws   = ws;
  float* Kws   = Qws + QKV;
  float* Vws   = Kws + QKV;
  float* partials = Vws + QKV;                // 786,432
  float* ktkWs = partials + (size_t)H*16*4096;// H*4096
  float* invWs = ktkWs + (size_t)H*4096;      // H*4096
  float* levWs = invWs + (size_t)H*4096;
  ushort* Xh  = (ushort*)(levWs + (size_t)H*S);   // input split / later CTX
  ushort* Xl  = Xh + QKV;
  ushort* Wqh = Xl + QKV;  ushort* Wql = Wqh + WSZ;
  ushort* Wkh = Wql + WSZ; ushort* Wkl = Wkh + WSZ;
  ushort* Wvh = Wkl + WSZ; ushort* Wvl = Wvh + WSZ;
  ushort* Woh = Wvl + WSZ; ushort* Wol = Woh + WSZ;
  ushort* KCh  = Wol + WSZ;
  ushort* KCl  = KCh  + (size_t)B*H*TOPK*DH;
  ushort* VCth = KCl  + (size_t)B*H*TOPK*DH;
  ushort* VCtl = VCth + (size_t)B*H*TOPK*DH;
  int*   idxWs = (int*)(VCtl + (size_t)B*H*TOPK*DH);

  const int nW8 = (int)(WSZ/8), nX8 = (int)(QKV/8);
  splitw4_kernel<<<dim3(nW8/256, 1, 4), 256, 0, stream>>>(Wq, Wk, Wv, Wo, Wqh, nW8);

  dim3 pgrid(NROW/64, D/64);
  split_kernel<<<nX8/256, 256, 0, stream>>>(query, Xh, Xl, nX8);
  projmf_kernel<1><<<pgrid, 256, 0, stream>>>(Xh, Xl, Wqh, Wql, bq, Qws, 0.125f);
  split_kernel<<<nX8/256, 256, 0, stream>>>(key, Xh, Xl, nX8);
  projmf_kernel<1><<<pgrid, 256, 0, stream>>>(Xh, Xl, Wkh, Wkl, bk, Kws, 1.0f);
  split_kernel<<<nX8/256, 256, 0, stream>>>(value, Xh, Xl, nX8);
  projmf_kernel<1><<<pgrid, 256, 0, stream>>>(Xh, Xl, Wvh, Wvl, bv, Vws, 1.0f);

  levA1_kernel<<<dim3(H,16), 256, 0, stream>>>(Kws, partials);
  levA0_kernel<<<(H*4096)/256, 256, 0, stream>>>(partials, ktkWs);
  levA2_kernel<<<H, 256, 0, stream>>>(ktkWs, invWs);
  levB_kernel<<<dim3(H,8), 256, 0, stream>>>(Kws, invWs, levWs);
  topk_kernel<<<H, 256, 0, stream>>>(levWs, idxWs);

  gather_kernel<<<dim3(B*H, TOPK/64), 256, 0, stream>>>(
      Kws, Vws, idxWs, KCh, KCl, VCth, VCtl);

  // attn writes CTX split into Xh/Xl (input splits are dead by now)
  attn_kernel<<<B*H*(S/64), 256, 0, stream>>>(Qws, KCh, KCl, VCth, VCtl, Xh, Xl);

  projmf_kernel<0><<<pgrid, 256, 0, stream>>>(Xh, Xl, Woh, Wol, bo, out, 1.0f);
}

// Round 8
// 679.568 us; speedup vs baseline: 1.1607x; 1.1607x over previous
//
#include <hip/hip_runtime.h>

#define B 2
#define S 2048
#define D 768
#define H 12
#define DH 64
#define TOPK 512
#define NROW (B*S)   // 4096

typedef __attribute__((ext_vector_type(8))) short bf16x8;
typedef __attribute__((ext_vector_type(8))) ushort u16x8;
typedef __attribute__((ext_vector_type(4))) float f32x4;

// ---- bf16 split helpers (hi = RNE bf16 of x, lo = RNE bf16 of residual) ----
__device__ __forceinline__ ushort bf16_hi(float x) {
  union { float f; unsigned u; } v; v.f = x;
  unsigned r = v.u + 0x7fffu + ((v.u >> 16) & 1u);
  return (ushort)(r >> 16);
}
__device__ __forceinline__ float bf16_tof(ushort h) {
  union { float f; unsigned u; } v; v.u = ((unsigned)h) << 16; return v.f;
}
__device__ __forceinline__ void bf16_split(float x, ushort& h, ushort& l) {
  h = bf16_hi(x);
  l = bf16_hi(x - bf16_tof(h));
}

// ---------------------------------------------------------------------------
// Split fp32 tensor -> bf16 hi/lo buffers. 8 elements/thread.
// ---------------------------------------------------------------------------
__global__ __launch_bounds__(256) void split_kernel(
    const float* __restrict__ src, ushort* __restrict__ dh,
    ushort* __restrict__ dl, int n8) {
  int i = blockIdx.x*256 + threadIdx.x;
  if (i >= n8) return;
  float v[8];
  *(float4*)&v[0] = ((const float4*)src)[i*2];
  *(float4*)&v[4] = ((const float4*)src)[i*2+1];
  ushort hh[8], ll[8];
#pragma unroll
  for (int k = 0; k < 8; ++k) bf16_split(v[k], hh[k], ll[k]);
  ((u16x8*)dh)[i] = *(u16x8*)&hh[0];
  ((u16x8*)dl)[i] = *(u16x8*)&ll[0];
}

// ---------------------------------------------------------------------------
// Fused 4-way weight split (z = 0..3 selects Wq/Wk/Wv/Wo).
// ---------------------------------------------------------------------------
__global__ __launch_bounds__(256) void splitw4_kernel(
    const float* __restrict__ w0, const float* __restrict__ w1,
    const float* __restrict__ w2, const float* __restrict__ w3,
    ushort* __restrict__ dbase, int n8) {
  int z = blockIdx.z;
  const float* src = (z == 0) ? w0 : (z == 1) ? w1 : (z == 2) ? w2 : w3;
  ushort* dh = dbase + (size_t)z * 2u * (size_t)(D*D);
  ushort* dl = dh + (size_t)(D*D);
  int i = blockIdx.x*256 + threadIdx.x;
  if (i >= n8) return;
  float v[8];
  *(float4*)&v[0] = ((const float4*)src)[i*2];
  *(float4*)&v[4] = ((const float4*)src)[i*2+1];
  ushort hh[8], ll[8];
#pragma unroll
  for (int k = 0; k < 8; ++k) bf16_split(v[k], hh[k], ll[k]);
  ((u16x8*)dh)[i] = *(u16x8*)&hh[0];
  ((u16x8*)dl)[i] = *(u16x8*)&ll[0];
}

// ---------------------------------------------------------------------------
// Split-bf16 MFMA GEMM: C = A (N x 768) @ W^T + bias, * scale
// TERMS=4: ah*wh + ah*wl + al*wh + al*wl (~fp32 exact; used for K-proj so
//          the leverage/top-k path is bit-identical across rounds)
// TERMS=3: drops al*wl (~1.5e-5 rel; smooth paths only)
// MODE 0: C row-major [N][768] fp32; MODE 1: C scattered to [b][h][s][dh]
// ---------------------------------------------------------------------------
template<int MODE, int TERMS>
__global__ __launch_bounds__(256) void projmf_kernel(
    const ushort* __restrict__ Ah, const ushort* __restrict__ Al,
    const ushort* __restrict__ Wh, const ushort* __restrict__ Wl,
    const float* __restrict__ bias, float* __restrict__ C, float scale) {
  int tid = threadIdx.x;
  int w = tid >> 6, lane = tid & 63;
  int lr = lane & 15, lg = lane >> 4;
  int n0 = blockIdx.x*64 + (w >> 1)*32;
  int m0 = blockIdx.y*64 + (w & 1)*32;
  f32x4 acc[2][2] = {};
  for (int ks = 0; ks < 24; ++ks) {
    int ko = ks*32 + lg*8;
    bf16x8 ah[2], al[2], wh[2], wl[2];
#pragma unroll
    for (int i = 0; i < 2; ++i) {
      size_t ao = (size_t)(n0 + 16*i + lr)*768 + ko;
      ah[i] = *(const bf16x8*)(Ah + ao);
      al[i] = *(const bf16x8*)(Al + ao);
      size_t wo = (size_t)(m0 + 16*i + lr)*768 + ko;
      wh[i] = *(const bf16x8*)(Wh + wo);
      wl[i] = *(const bf16x8*)(Wl + wo);
    }
#pragma unroll
    for (int i = 0; i < 2; ++i)
#pragma unroll
      for (int j = 0; j < 2; ++j) {
        acc[i][j] = __builtin_amdgcn_mfma_f32_16x16x32_bf16(ah[i], wh[j], acc[i][j], 0, 0, 0);
        acc[i][j] = __builtin_amdgcn_mfma_f32_16x16x32_bf16(ah[i], wl[j], acc[i][j], 0, 0, 0);
        acc[i][j] = __builtin_amdgcn_mfma_f32_16x16x32_bf16(al[i], wh[j], acc[i][j], 0, 0, 0);
        if (TERMS == 4)
          acc[i][j] = __builtin_amdgcn_mfma_f32_16x16x32_bf16(al[i], wl[j], acc[i][j], 0, 0, 0);
      }
  }
#pragma unroll
  for (int i = 0; i < 2; ++i)
#pragma unroll
    for (int j = 0; j < 2; ++j) {
      int m = m0 + 16*j + lr;
      float bv = bias[m];
#pragma unroll
      for (int r = 0; r < 4; ++r) {
        int n = n0 + 16*i + lg*4 + r;
        float val = (acc[i][j][r] + bv) * scale;
        if (MODE == 0) {
          C[(size_t)n*D + m] = val;
        } else {
          int b = n >> 11, s = n & 2047, hh = m >> 6, dh = m & 63;
          C[(((size_t)b*H + hh)*S + s)*DH + dh] = val;
        }
      }
    }
}

// ---------------------------------------------------------------------------
// Leverage stage A1: per-head partial KtK over 128-row chunks (batch 0 only)
// ---------------------------------------------------------------------------
__global__ __launch_bounds__(256) void levA1_kernel(
    const float* __restrict__ Kmat, float* __restrict__ partials) {
  int h = blockIdx.x, blk = blockIdx.y;
  __shared__ __align__(16) float ktile[128*64];
  int tid = threadIdx.x;
  const float* Kh = Kmat + ((size_t)h*S + (size_t)blk*128)*DH;
#pragma unroll
  for (int r = 0; r < 32; ++r) { int e = tid + 256*r; ktile[e] = Kh[e]; }
  __syncthreads();
  int j4 = tid & 15;
  float accf[4][4] = {};
  for (int ss = 0; ss < 128; ++ss) {
    float4 kj = ((const float4*)(ktile + ss*64))[j4];
#pragma unroll
    for (int r = 0; r < 4; ++r) {
      int i = (tid >> 4) + 16*r;
      float ki = ktile[ss*64 + i];
      accf[r][0] += ki*kj.x; accf[r][1] += ki*kj.y;
      accf[r][2] += ki*kj.z; accf[r][3] += ki*kj.w;
    }
  }
  size_t base = ((size_t)h*16 + blk)*4096;
#pragma unroll
  for (int r = 0; r < 4; ++r) {
    int i = (tid >> 4) + 16*r;
#pragma unroll
    for (int c = 0; c < 4; ++c)
      partials[base + (size_t)i*64 + j4*4 + c] = accf[r][c];
  }
}

// ---------------------------------------------------------------------------
// Leverage stage A0-reduce: wide parallel fp64 sum of the 16 partials
// (same p=0..15 order -> identical KtK) + damping.
// ---------------------------------------------------------------------------
__global__ __launch_bounds__(256) void levA0_kernel(
    const float* __restrict__ partials, float* __restrict__ KtK) {
  int g = blockIdx.x*256 + threadIdx.x;        // 0 .. H*4096-1
  int h = g >> 12, e = g & 4095;
  const float* pb = partials + (size_t)h*65536 + e;
  double t = 0.0;
#pragma unroll
  for (int p = 0; p < 16; ++p) t += (double)pb[(size_t)p*4096];
  if ((e >> 6) == (e & 63)) t += 1e-6;
  KtK[g] = (float)t;
}

// ---------------------------------------------------------------------------
// Leverage stage A2 (v5): phase-split Gauss-Jordan, MINIMAL cross-barrier
// live state. One block (256 thr) per head; thread (r = tid&63, q = tid>>6)
// owns cols [q*32, q*32+32) of augmented row r (stride 131 -> conflict-free).
// READ phase registers only the CROSS-THREAD values: pv[16] (pivot-row
// chunk), f (own row col p - may be written by a sibling thread of the same
// row next phase), ipiv. ~34 VGPRs live across the barrier (v4's 64+ spilled
// at the allocator's 52-reg occupancy cap -> scratch -> 310us).
// __launch_bounds__(256, 1) frees the allocator. ov (own cols, self-written
// only) is read inside the WRITE phase - race-free by ownership.
// ---------------------------------------------------------------------------
__global__ __launch_bounds__(256, 1) void levA2_kernel(
    const float* __restrict__ KtK, float* __restrict__ invOut) {
  __shared__ float A_[64*131 + 1];
  int h = blockIdx.x, tid = threadIdx.x;
  int r = tid & 63, q = tid >> 6;
  int c0 = q * 32;
  float* row = A_ + r*131;
  const float* src = KtK + (size_t)h*4096 + r*64;
#pragma unroll
  for (int i = 0; i < 32; ++i) {
    int c = c0 + i;
    row[c] = (c < 64) ? src[c] : ((c - 64 == r) ? 1.0f : 0.0f);
  }
  __syncthreads();
  for (int p = 0; p < 64; ++p) {
    // ---- read phase: cross-thread values -> registers ----
    float f = row[p];                    // own row, col p (pre-update)
    float piv = A_[p*131 + p];           // A[p][p]
    float ipiv = 1.0f / piv;
    bool isp = (r == p);
    const float* prow = A_ + p*131;
    float2 pv[16];
#pragma unroll
    for (int i = 0; i < 16; ++i) pv[i] = *(const float2*)&prow[c0 + 2*i];
    __syncthreads();
    // ---- write phase: own row/cols only (self-written -> race-free) ----
#pragma unroll
    for (int i = 0; i < 16; ++i) {
      float2 ov = *(const float2*)&row[c0 + 2*i];
      float n0 = pv[i].x * ipiv, n1 = pv[i].y * ipiv;
      float o0 = isp ? n0 : fmaf(-f, n0, ov.x);
      float o1 = isp ? n1 : fmaf(-f, n1, ov.y);
      *(float2*)&row[c0 + 2*i] = make_float2(o0, o1);
    }
    __syncthreads();
  }
  // extract inverse (cols 64..127)
  size_t obase = (size_t)h*4096 + (size_t)tid*16;
#pragma unroll
  for (int i = 0; i < 16; ++i) {
    int e = tid*16 + i;
    invOut[obase + i] = A_[(e >> 6)*131 + 64 + (e & 63)];
  }
}

// ---------------------------------------------------------------------------
// Leverage stage B: lev[h][s] = k_s^T inv_h k_s
// ---------------------------------------------------------------------------
__global__ __launch_bounds__(256) void levB_kernel(
    const float* __restrict__ Kmat, const float* __restrict__ invMat,
    float* __restrict__ lev) {
  int h = blockIdx.x;
  int s = blockIdx.y*256 + threadIdx.x;
  __shared__ __align__(16) float inv[64*64];
#pragma unroll
  for (int r = 0; r < 16; ++r)
    inv[threadIdx.x + 256*r] = invMat[(size_t)h*4096 + threadIdx.x + 256*r];
  __syncthreads();
  float kv[64];
  const float* kr = Kmat + ((size_t)h*S + s)*DH;
#pragma unroll
  for (int d4 = 0; d4 < 16; ++d4) {
    float4 t = ((const float4*)kr)[d4];
    kv[4*d4+0]=t.x; kv[4*d4+1]=t.y; kv[4*d4+2]=t.z; kv[4*d4+3]=t.w;
  }
  float acc = 0.f;
  for (int i = 0; i < 64; ++i) {
    float ti = 0.f;
    const float4* ir = (const float4*)(inv + i*64);
#pragma unroll
    for (int j4 = 0; j4 < 16; ++j4) {
      float4 iv = ir[j4];
      ti += iv.x*kv[4*j4] + iv.y*kv[4*j4+1] + iv.z*kv[4*j4+2] + iv.w*kv[4*j4+3];
    }
    acc += ti * kv[i];
  }
  lev[(size_t)h*S + s] = acc;
}

// ---------------------------------------------------------------------------
// Top-k via bitonic sort (value desc, index asc)
// ---------------------------------------------------------------------------
__global__ __launch_bounds__(256) void topk_kernel(
    const float* __restrict__ lev, int* __restrict__ idx_list) {
  int h = blockIdx.x, tid = threadIdx.x;
  __shared__ float sv[2048];
  __shared__ int   si[2048];
#pragma unroll
  for (int r = 0; r < 8; ++r) {
    int e = tid + 256*r;
    sv[e] = lev[(size_t)h*S + e];
    si[e] = e;
  }
  __syncthreads();
  for (int k = 2; k <= 2048; k <<= 1) {
    for (int j = k >> 1; j > 0; j >>= 1) {
      for (int r = 0; r < 8; ++r) {
        int i = tid + 256*r;
        int l = i ^ j;
        if (l > i) {
          float v1 = sv[i], v2 = sv[l];
          int   i1 = si[i], i2 = si[l];
          bool before = (v1 > v2) || (v1 == v2 && i1 < i2);
          bool dir = ((i & k) == 0);
          if (before != dir) { sv[i]=v2; sv[l]=v1; si[i]=i2; si[l]=i1; }
        }
      }
      __syncthreads();
    }
  }
#pragma unroll
  for (int r = 0; r < 2; ++r) {
    int t = tid + 256*r;
    idx_list[h*TOPK + t] = si[t];
  }
}

// ---------------------------------------------------------------------------
// Gather kept K/V rows -> bf16 split buffers.
// KCh/KCl: [bh][512][64]; VCth/VCtl: [bh][64][512] (transposed)
// ---------------------------------------------------------------------------
__global__ __launch_bounds__(256) void gather_kernel(
    const float* __restrict__ Kmat, const float* __restrict__ Vmat,
    const int* __restrict__ idx_list,
    ushort* __restrict__ KCh, ushort* __restrict__ KCl,
    ushort* __restrict__ VCth, ushort* __restrict__ VCtl) {
  int bh = blockIdx.x;        // 0..23
  int kc = blockIdx.y;        // 0..7
  int h = bh % H;
  __shared__ float vt[64][65];
  int tid = threadIdx.x;
  int kk = tid >> 2;           // key within chunk (0..63)
  int dq = (tid & 3) * 16;     // dh base (0,16,32,48)
  int j = kc*64 + kk;
  int srow = idx_list[h*TOPK + j];
  const float* kr = Kmat + ((size_t)bh*S + srow)*DH + dq;
  const float* vr = Vmat + ((size_t)bh*S + srow)*DH + dq;
  ushort hh[16], ll[16];
#pragma unroll
  for (int i = 0; i < 16; ++i) bf16_split(kr[i], hh[i], ll[i]);
  size_t kbase = ((size_t)bh*TOPK + j)*DH + dq;
  *(u16x8*)(KCh + kbase)     = *(u16x8*)&hh[0];
  *(u16x8*)(KCh + kbase + 8) = *(u16x8*)&hh[8];
  *(u16x8*)(KCl + kbase)     = *(u16x8*)&ll[0];
  *(u16x8*)(KCl + kbase + 8) = *(u16x8*)&ll[8];
#pragma unroll
  for (int i = 0; i < 16; ++i) vt[kk][dq + i] = vr[i];
  __syncthreads();
  int d  = tid >> 2;           // dh row (0..63)
  int kq = (tid & 3) * 16;     // key base within chunk
#pragma unroll
  for (int i = 0; i < 16; ++i) bf16_split(vt[kq + i][d], hh[i], ll[i]);
  size_t vbase = ((size_t)bh*DH + d)*TOPK + kc*64 + kq;
  *(u16x8*)(VCth + vbase)     = *(u16x8*)&hh[0];
  *(u16x8*)(VCth + vbase + 8) = *(u16x8*)&hh[8];
  *(u16x8*)(VCtl + vbase)     = *(u16x8*)&ll[0];
  *(u16x8*)(VCtl + vbase + 8) = *(u16x8*)&ll[8];
}

// ---------------------------------------------------------------------------
// MFMA attention, split-bf16: single pass, 4 waves/block, wave-private LDS.
// Epilogue writes CTX as bf16 hi/lo (feeds the MFMA output projection).
// ---------------------------------------------------------------------------
__global__ __launch_bounds__(256) void attn_kernel(
    const float* __restrict__ Q,
    const ushort* __restrict__ KCh, const ushort* __restrict__ KCl,
    const ushort* __restrict__ VCth, const ushort* __restrict__ VCtl,
    ushort* __restrict__ CTXh, ushort* __restrict__ CTXl) {
  __shared__ __align__(16) ushort SQh[4][16][88];
  __shared__ __align__(16) ushort SQl[4][16][88];
  int tid = threadIdx.x;
  int w = tid >> 6;
  int lane = tid & 63;
  int lr = lane & 15, lg = lane >> 4;
  int bh = blockIdx.x >> 5;
  int qt = blockIdx.x & 31;
  int qbase = qt*64 + w*16;
  int b = bh / H, h = bh % H;

  bf16x8 qh[2], ql[2];
#pragma unroll
  for (int ks = 0; ks < 2; ++ks) {
    const float* qp = Q + ((size_t)bh*S + qbase + lr)*DH + ks*32 + lg*8;
    float qv[8];
    *(float4*)&qv[0] = *(const float4*)qp;
    *(float4*)&qv[4] = *(const float4*)(qp + 4);
#pragma unroll
    for (int i = 0; i < 8; ++i) {
      ushort hh, lo; bf16_split(qv[i], hh, lo);
      qh[ks][i] = (short)hh; ql[ks][i] = (short)lo;
    }
  }

  f32x4 pacc[4] = {};
  float z_acc[4] = {};

  for (int c = 0; c < 8; ++c) {
    int keybase = c*64;
    f32x4 sacc[4] = {};
#pragma unroll
    for (int ks = 0; ks < 2; ++ks) {
#pragma unroll
      for (int f = 0; f < 4; ++f) {
        size_t koff = ((size_t)bh*TOPK + keybase + 16*f + lr)*DH + ks*32 + lg*8;
        bf16x8 kh = *(const bf16x8*)(KCh + koff);
        bf16x8 kl = *(const bf16x8*)(KCl + koff);
        sacc[f] = __builtin_amdgcn_mfma_f32_16x16x32_bf16(qh[ks], kh, sacc[f], 0, 0, 0);
        sacc[f] = __builtin_amdgcn_mfma_f32_16x16x32_bf16(qh[ks], kl, sacc[f], 0, 0, 0);
        sacc[f] = __builtin_amdgcn_mfma_f32_16x16x32_bf16(ql[ks], kh, sacc[f], 0, 0, 0);
      }
    }
    float zc[4] = {};
#pragma unroll
    for (int f = 0; f < 4; ++f) {
#pragma unroll
      for (int r = 0; r < 4; ++r) {
        float s = sacc[f][r];
        float sq = s*s;
        zc[r] += sq;
        ushort hh, lo; bf16_split(sq, hh, lo);
        SQh[w][lg*4 + r][16*f + lr] = hh;
        SQl[w][lg*4 + r][16*f + lr] = lo;
      }
    }
#pragma unroll
    for (int r = 0; r < 4; ++r) {
      float t = zc[r];
      t += __shfl_xor(t, 1);
      t += __shfl_xor(t, 2);
      t += __shfl_xor(t, 4);
      t += __shfl_xor(t, 8);
      z_acc[r] += t;
    }
#pragma unroll
    for (int ks = 0; ks < 2; ++ks) {
      bf16x8 ah = *(const bf16x8*)&SQh[w][lr][ks*32 + lg*8];
      bf16x8 al = *(const bf16x8*)&SQl[w][lr][ks*32 + lg*8];
#pragma unroll
      for (int f = 0; f < 4; ++f) {
        size_t voff = ((size_t)bh*DH + 16*f + lr)*TOPK + keybase + ks*32 + lg*8;
        bf16x8 vh = *(const bf16x8*)(VCth + voff);
        bf16x8 vl = *(const bf16x8*)(VCtl + voff);
        pacc[f] = __builtin_amdgcn_mfma_f32_16x16x32_bf16(ah, vh, pacc[f], 0, 0, 0);
        pacc[f] = __builtin_amdgcn_mfma_f32_16x16x32_bf16(ah, vl, pacc[f], 0, 0, 0);
        pacc[f] = __builtin_amdgcn_mfma_f32_16x16x32_bf16(al, vh, pacc[f], 0, 0, 0);
      }
    }
  }

  float zi[4];
#pragma unroll
  for (int r = 0; r < 4; ++r) zi[r] = 1.0f / (z_acc[r] + 1e-12f);
#pragma unroll
  for (int f = 0; f < 4; ++f) {
#pragma unroll
    for (int r = 0; r < 4; ++r) {
      int q = lg*4 + r;
      float val = pacc[f][r] * zi[r];
      ushort hh, lo; bf16_split(val, hh, lo);
      size_t o = ((size_t)b*S + qbase + q)*D + h*DH + 16*f + lr;
      CTXh[o] = hh; CTXl[o] = lo;
    }
  }
}

// ---------------------------------------------------------------------------
extern "C" void kernel_launch(void* const* d_in, const int* in_sizes, int n_in,
                              void* d_out, int out_size, void* d_ws, size_t ws_size,
                              hipStream_t stream) {
  const float* query = (const float*)d_in[0];
  const float* key   = (const float*)d_in[1];
  const float* value = (const float*)d_in[2];
  const float* Wq = (const float*)d_in[3];
  const float* bq = (const float*)d_in[4];
  const float* Wk = (const float*)d_in[5];
  const float* bk = (const float*)d_in[6];
  const float* Wv = (const float*)d_in[7];
  const float* bv = (const float*)d_in[8];
  const float* Wo = (const float*)d_in[9];
  const float* bo = (const float*)d_in[10];
  float* out = (float*)d_out;

  float* ws = (float*)d_ws;
  const size_t QKV = (size_t)B*H*S*DH;        // 3,145,728
  const size_t WSZ = (size_t)D*D;             // 589,824
  float* Qws   = ws;
  float* Kws   = Qws + QKV;
  float* Vws   = Kws + QKV;
  float* partials = Vws + QKV;                // 786,432
  float* ktkWs = partials + (size_t)H*16*4096;// H*4096
  float* invWs = ktkWs + (size_t)H*4096;      // H*4096
  float* levWs = invWs + (size_t)H*4096;
  ushort* Xh  = (ushort*)(levWs + (size_t)H*S);   // input split / later CTX
  ushort* Xl  = Xh + QKV;
  ushort* Wqh = Xl + QKV;  ushort* Wql = Wqh + WSZ;
  ushort* Wkh = Wql + WSZ; ushort* Wkl = Wkh + WSZ;
  ushort* Wvh = Wkl + WSZ; ushort* Wvl = Wvh + WSZ;
  ushort* Woh = Wvl + WSZ; ushort* Wol = Woh + WSZ;
  ushort* KCh  = Wol + WSZ;
  ushort* KCl  = KCh  + (size_t)B*H*TOPK*DH;
  ushort* VCth = KCl  + (size_t)B*H*TOPK*DH;
  ushort* VCtl = VCth + (size_t)B*H*TOPK*DH;
  int*   idxWs = (int*)(VCtl + (size_t)B*H*TOPK*DH);

  const int nW8 = (int)(WSZ/8), nX8 = (int)(QKV/8);
  splitw4_kernel<<<dim3(nW8/256, 1, 4), 256, 0, stream>>>(Wq, Wk, Wv, Wo, Wqh, nW8);

  dim3 pgrid(NROW/64, D/64);
  split_kernel<<<nX8/256, 256, 0, stream>>>(query, Xh, Xl, nX8);
  projmf_kernel<1,3><<<pgrid, 256, 0, stream>>>(Xh, Xl, Wqh, Wql, bq, Qws, 0.125f);
  split_kernel<<<nX8/256, 256, 0, stream>>>(key, Xh, Xl, nX8);
  projmf_kernel<1,4><<<pgrid, 256, 0, stream>>>(Xh, Xl, Wkh, Wkl, bk, Kws, 1.0f);
  split_kernel<<<nX8/256, 256, 0, stream>>>(value, Xh, Xl, nX8);
  projmf_kernel<1,3><<<pgrid, 256, 0, stream>>>(Xh, Xl, Wvh, Wvl, bv, Vws, 1.0f);

  levA1_kernel<<<dim3(H,16), 256, 0, stream>>>(Kws, partials);
  levA0_kernel<<<(H*4096)/256, 256, 0, stream>>>(partials, ktkWs);
  levA2_kernel<<<H, 256, 0, stream>>>(ktkWs, invWs);
  levB_kernel<<<dim3(H,8), 256, 0, stream>>>(Kws, invWs, levWs);
  topk_kernel<<<H, 256, 0, stream>>>(levWs, idxWs);

  gather_kernel<<<dim3(B*H, TOPK/64), 256, 0, stream>>>(
      Kws, Vws, idxWs, KCh, KCl, VCth, VCtl);

  // attn writes CTX split into Xh/Xl (input splits are dead by now)
  attn_kernel<<<B*H*(S/64), 256, 0, stream>>>(Qws, KCh, KCl, VCth, VCtl, Xh, Xl);

  projmf_kernel<0,3><<<pgrid, 256, 0, stream>>>(Xh, Xl, Woh, Wol, bo, out, 1.0f);
}

// Round 9
// 509.034 us; speedup vs baseline: 1.5496x; 1.3350x over previous
//
#include <hip/hip_runtime.h>

#define B 2
#define S 2048
#define D 768
#define H 12
#define DH 64
#define TOPK 512
#define NROW (B*S)   // 4096

typedef __attribute__((ext_vector_type(8))) short bf16x8;
typedef __attribute__((ext_vector_type(8))) ushort u16x8;
typedef __attribute__((ext_vector_type(4))) float f32x4;

// ---- bf16 split helpers (hi = RNE bf16 of x, lo = RNE bf16 of residual) ----
__device__ __forceinline__ ushort bf16_hi(float x) {
  union { float f; unsigned u; } v; v.f = x;
  unsigned r = v.u + 0x7fffu + ((v.u >> 16) & 1u);
  return (ushort)(r >> 16);
}
__device__ __forceinline__ float bf16_tof(ushort h) {
  union { float f; unsigned u; } v; v.u = ((unsigned)h) << 16; return v.f;
}
__device__ __forceinline__ void bf16_split(float x, ushort& h, ushort& l) {
  h = bf16_hi(x);
  l = bf16_hi(x - bf16_tof(h));
}

// ---------------------------------------------------------------------------
// Split fp32 tensor -> bf16 hi/lo buffers. 8 elements/thread.
// ---------------------------------------------------------------------------
__global__ __launch_bounds__(256) void split_kernel(
    const float* __restrict__ src, ushort* __restrict__ dh,
    ushort* __restrict__ dl, int n8) {
  int i = blockIdx.x*256 + threadIdx.x;
  if (i >= n8) return;
  float v[8];
  *(float4*)&v[0] = ((const float4*)src)[i*2];
  *(float4*)&v[4] = ((const float4*)src)[i*2+1];
  ushort hh[8], ll[8];
#pragma unroll
  for (int k = 0; k < 8; ++k) bf16_split(v[k], hh[k], ll[k]);
  ((u16x8*)dh)[i] = *(u16x8*)&hh[0];
  ((u16x8*)dl)[i] = *(u16x8*)&ll[0];
}

// ---------------------------------------------------------------------------
// Fused 4-way weight split (z = 0..3 selects Wq/Wk/Wv/Wo).
// ---------------------------------------------------------------------------
__global__ __launch_bounds__(256) void splitw4_kernel(
    const float* __restrict__ w0, const float* __restrict__ w1,
    const float* __restrict__ w2, const float* __restrict__ w3,
    ushort* __restrict__ dbase, int n8) {
  int z = blockIdx.z;
  const float* src = (z == 0) ? w0 : (z == 1) ? w1 : (z == 2) ? w2 : w3;
  ushort* dh = dbase + (size_t)z * 2u * (size_t)(D*D);
  ushort* dl = dh + (size_t)(D*D);
  int i = blockIdx.x*256 + threadIdx.x;
  if (i >= n8) return;
  float v[8];
  *(float4*)&v[0] = ((const float4*)src)[i*2];
  *(float4*)&v[4] = ((const float4*)src)[i*2+1];
  ushort hh[8], ll[8];
#pragma unroll
  for (int k = 0; k < 8; ++k) bf16_split(v[k], hh[k], ll[k]);
  ((u16x8*)dh)[i] = *(u16x8*)&hh[0];
  ((u16x8*)dl)[i] = *(u16x8*)&ll[0];
}

// ---------------------------------------------------------------------------
// Split-bf16 MFMA GEMM: C = A (N x 768) @ W^T + bias, * scale
// TERMS=4 (~fp32 exact; K-proj -> leverage path stable)
// TERMS=3 (drops al*wl, ~1.5e-5 rel; smooth paths)
// ---------------------------------------------------------------------------
template<int MODE, int TERMS>
__global__ __launch_bounds__(256) void projmf_kernel(
    const ushort* __restrict__ Ah, const ushort* __restrict__ Al,
    const ushort* __restrict__ Wh, const ushort* __restrict__ Wl,
    const float* __restrict__ bias, float* __restrict__ C, float scale) {
  int tid = threadIdx.x;
  int w = tid >> 6, lane = tid & 63;
  int lr = lane & 15, lg = lane >> 4;
  int n0 = blockIdx.x*64 + (w >> 1)*32;
  int m0 = blockIdx.y*64 + (w & 1)*32;
  f32x4 acc[2][2] = {};
  for (int ks = 0; ks < 24; ++ks) {
    int ko = ks*32 + lg*8;
    bf16x8 ah[2], al[2], wh[2], wl[2];
#pragma unroll
    for (int i = 0; i < 2; ++i) {
      size_t ao = (size_t)(n0 + 16*i + lr)*768 + ko;
      ah[i] = *(const bf16x8*)(Ah + ao);
      al[i] = *(const bf16x8*)(Al + ao);
      size_t wo = (size_t)(m0 + 16*i + lr)*768 + ko;
      wh[i] = *(const bf16x8*)(Wh + wo);
      wl[i] = *(const bf16x8*)(Wl + wo);
    }
#pragma unroll
    for (int i = 0; i < 2; ++i)
#pragma unroll
      for (int j = 0; j < 2; ++j) {
        acc[i][j] = __builtin_amdgcn_mfma_f32_16x16x32_bf16(ah[i], wh[j], acc[i][j], 0, 0, 0);
        acc[i][j] = __builtin_amdgcn_mfma_f32_16x16x32_bf16(ah[i], wl[j], acc[i][j], 0, 0, 0);
        acc[i][j] = __builtin_amdgcn_mfma_f32_16x16x32_bf16(al[i], wh[j], acc[i][j], 0, 0, 0);
        if (TERMS == 4)
          acc[i][j] = __builtin_amdgcn_mfma_f32_16x16x32_bf16(al[i], wl[j], acc[i][j], 0, 0, 0);
      }
  }
#pragma unroll
  for (int i = 0; i < 2; ++i)
#pragma unroll
    for (int j = 0; j < 2; ++j) {
      int m = m0 + 16*j + lr;
      float bv = bias[m];
#pragma unroll
      for (int r = 0; r < 4; ++r) {
        int n = n0 + 16*i + lg*4 + r;
        float val = (acc[i][j][r] + bv) * scale;
        if (MODE == 0) {
          C[(size_t)n*D + m] = val;
        } else {
          int b = n >> 11, s = n & 2047, hh = m >> 6, dh = m & 63;
          C[(((size_t)b*H + hh)*S + s)*DH + dh] = val;
        }
      }
    }
}

// ---------------------------------------------------------------------------
// Leverage stage A1: per-head partial KtK over 128-row chunks (batch 0 only)
// ---------------------------------------------------------------------------
__global__ __launch_bounds__(256) void levA1_kernel(
    const float* __restrict__ Kmat, float* __restrict__ partials) {
  int h = blockIdx.x, blk = blockIdx.y;
  __shared__ __align__(16) float ktile[128*64];
  int tid = threadIdx.x;
  const float* Kh = Kmat + ((size_t)h*S + (size_t)blk*128)*DH;
#pragma unroll
  for (int r = 0; r < 32; ++r) { int e = tid + 256*r; ktile[e] = Kh[e]; }
  __syncthreads();
  int j4 = tid & 15;
  float accf[4][4] = {};
  for (int ss = 0; ss < 128; ++ss) {
    float4 kj = ((const float4*)(ktile + ss*64))[j4];
#pragma unroll
    for (int r = 0; r < 4; ++r) {
      int i = (tid >> 4) + 16*r;
      float ki = ktile[ss*64 + i];
      accf[r][0] += ki*kj.x; accf[r][1] += ki*kj.y;
      accf[r][2] += ki*kj.z; accf[r][3] += ki*kj.w;
    }
  }
  size_t base = ((size_t)h*16 + blk)*4096;
#pragma unroll
  for (int r = 0; r < 4; ++r) {
    int i = (tid >> 4) + 16*r;
#pragma unroll
    for (int c = 0; c < 4; ++c)
      partials[base + (size_t)i*64 + j4*4 + c] = accf[r][c];
  }
}

// ---------------------------------------------------------------------------
// Leverage stage A0-reduce: wide parallel fp64 sum of the 16 partials
// (same p=0..15 order -> identical KtK) + damping.
// ---------------------------------------------------------------------------
__global__ __launch_bounds__(256) void levA0_kernel(
    const float* __restrict__ partials, float* __restrict__ KtK) {
  int g = blockIdx.x*256 + threadIdx.x;        // 0 .. H*4096-1
  int h = g >> 12, e = g & 4095;
  const float* pb = partials + (size_t)h*65536 + e;
  double t = 0.0;
#pragma unroll
  for (int p = 0; p < 16; ++p) t += (double)pb[(size_t)p*4096];
  if ((e >> 6) == (e & 63)) t += 1e-6;
  KtK[g] = (float)t;
}

// ---------------------------------------------------------------------------
// Newton-iteration inverse via MFMA (replaces pivot-serial Gauss-Jordan,
// which was latency-floored at ~200us: 64 serial pivots x 2 barriers x
// wave-wide LDS round-trips). One block (256 thr, 4 waves) per head.
//   A = KtK (SPD, strongly diag-dominant: diag ~ 620, offdiag ~ +-14)
//   X0 = I / ||A||inf  ->  ||I - X0 A|| ~ 0.7  ->  12 iters >> fp32 floor
//   iterate: T' = X*A^T (A sym), U = X*T'^T = X A X^T; X' = 2X - sym(U)
// sym(U) = 0.5(U+U^T) is bitwise symmetric (commutative add), so X stays
// bitwise symmetric and X A X^T == X A X exactly. 4-term split-bf16 MFMAs
// ~ fp32-exact; Newton is self-correcting. 3 barriers/iter, NO register
// state across barriers (each GEMM's acc dies into LDS pre-barrier).
// ---------------------------------------------------------------------------
__global__ __launch_bounds__(256) void newton_inv_kernel(
    const float* __restrict__ KtK, float* __restrict__ invOut) {
  const int SF = 68;   // fp32 LDS row stride
  const int SB = 72;   // bf16 LDS row stride
  __shared__ float Xf[64*SF];
  __shared__ float Uf[64*SF];
  __shared__ __align__(16) ushort Ah[64*SB], Al[64*SB];
  __shared__ __align__(16) ushort Xh[64*SB], Xl[64*SB];
  __shared__ __align__(16) ushort Th[64*SB], Tl[64*SB];
  __shared__ float rsum[64];
  __shared__ float csh;
  int h = blockIdx.x, tid = threadIdx.x;
  int w = tid >> 6, lane = tid & 63;
  int lr = lane & 15, lg = lane >> 4;
  int r = tid >> 2, qq = tid & 3;          // init map: row r, 16-col quarter

  // ---- init: load A row-chunk, split to bf16, row abs-sum ----
  float s = 0.f;
  {
    const float* src = KtK + (size_t)h*4096 + (size_t)r*64 + qq*16;
#pragma unroll
    for (int i = 0; i < 16; ++i) {
      float a = src[i];
      s += fabsf(a);
      ushort hh, ll; bf16_split(a, hh, ll);
      Ah[r*SB + qq*16 + i] = hh; Al[r*SB + qq*16 + i] = ll;
    }
    s += __shfl_xor(s, 1);
    s += __shfl_xor(s, 2);
    if (qq == 0) rsum[r] = s;
  }
  __syncthreads();
  if (tid < 64) {
    float m = rsum[tid];
#pragma unroll
    for (int o = 32; o; o >>= 1) m = fmaxf(m, __shfl_xor(m, o));
    if (tid == 0) csh = 1.0f / m;
  }
  __syncthreads();
  float c = csh;
  // X0 = c * I
#pragma unroll
  for (int i = 0; i < 16; ++i) {
    int e = qq*16 + i;
    float x0 = (e == r) ? c : 0.0f;
    Xf[r*SF + e] = x0;
    ushort hh, ll; bf16_split(x0, hh, ll);
    Xh[r*SB + e] = hh; Xl[r*SB + e] = ll;
  }
  __syncthreads();

  int n0 = (w >> 1)*32, m0 = (w & 1)*32;
  for (int it = 0; it < 12; ++it) {
    // ---- P1: T' = X * A^T ----
    {
      f32x4 acc[2][2] = {};
#pragma unroll
      for (int ks = 0; ks < 2; ++ks) {
        bf16x8 pah[2], pal[2], pbh[2], pbl[2];
#pragma unroll
        for (int i = 0; i < 2; ++i) {
          int ao = (n0 + 16*i + lr)*SB + ks*32 + lg*8;
          pah[i] = *(const bf16x8*)&Xh[ao]; pal[i] = *(const bf16x8*)&Xl[ao];
          int bo = (m0 + 16*i + lr)*SB + ks*32 + lg*8;
          pbh[i] = *(const bf16x8*)&Ah[bo]; pbl[i] = *(const bf16x8*)&Al[bo];
        }
#pragma unroll
        for (int i = 0; i < 2; ++i)
#pragma unroll
          for (int j = 0; j < 2; ++j) {
            acc[i][j] = __builtin_amdgcn_mfma_f32_16x16x32_bf16(pah[i], pbh[j], acc[i][j], 0, 0, 0);
            acc[i][j] = __builtin_amdgcn_mfma_f32_16x16x32_bf16(pah[i], pbl[j], acc[i][j], 0, 0, 0);
            acc[i][j] = __builtin_amdgcn_mfma_f32_16x16x32_bf16(pal[i], pbh[j], acc[i][j], 0, 0, 0);
            acc[i][j] = __builtin_amdgcn_mfma_f32_16x16x32_bf16(pal[i], pbl[j], acc[i][j], 0, 0, 0);
          }
      }
#pragma unroll
      for (int i = 0; i < 2; ++i)
#pragma unroll
        for (int j = 0; j < 2; ++j)
#pragma unroll
          for (int rr = 0; rr < 4; ++rr) {
            int n = n0 + 16*i + lg*4 + rr, m = m0 + 16*j + lr;
            ushort hh, ll; bf16_split(acc[i][j][rr], hh, ll);
            Th[n*SB + m] = hh; Tl[n*SB + m] = ll;
          }
    }
    __syncthreads();   // Th/Tl ready for P2
    // ---- P2: U = X * T'^T  (epilogue -> Uf fp32) ----
    {
      f32x4 acc[2][2] = {};
#pragma unroll
      for (int ks = 0; ks < 2; ++ks) {
        bf16x8 pah[2], pal[2], pbh[2], pbl[2];
#pragma unroll
        for (int i = 0; i < 2; ++i) {
          int ao = (n0 + 16*i + lr)*SB + ks*32 + lg*8;
          pah[i] = *(const bf16x8*)&Xh[ao]; pal[i] = *(const bf16x8*)&Xl[ao];
          int bo = (m0 + 16*i + lr)*SB + ks*32 + lg*8;
          pbh[i] = *(const bf16x8*)&Th[bo]; pbl[i] = *(const bf16x8*)&Tl[bo];
        }
#pragma unroll
        for (int i = 0; i < 2; ++i)
#pragma unroll
          for (int j = 0; j < 2; ++j) {
            acc[i][j] = __builtin_amdgcn_mfma_f32_16x16x32_bf16(pah[i], pbh[j], acc[i][j], 0, 0, 0);
            acc[i][j] = __builtin_amdgcn_mfma_f32_16x16x32_bf16(pah[i], pbl[j], acc[i][j], 0, 0, 0);
            acc[i][j] = __builtin_amdgcn_mfma_f32_16x16x32_bf16(pal[i], pbh[j], acc[i][j], 0, 0, 0);
            acc[i][j] = __builtin_amdgcn_mfma_f32_16x16x32_bf16(pal[i], pbl[j], acc[i][j], 0, 0, 0);
          }
      }
#pragma unroll
      for (int i = 0; i < 2; ++i)
#pragma unroll
        for (int j = 0; j < 2; ++j)
#pragma unroll
          for (int rr = 0; rr < 4; ++rr) {
            int n = n0 + 16*i + lg*4 + rr, m = m0 + 16*j + lr;
            Uf[n*SF + m] = acc[i][j][rr];
          }
    }
    __syncthreads();   // all P2 reads of Xh/Xl done; Uf ready
    // ---- P3: X' = 2X - 0.5(U + U^T)  (bitwise-symmetric update) ----
#pragma unroll
    for (int i = 0; i < 2; ++i)
#pragma unroll
      for (int j = 0; j < 2; ++j)
#pragma unroll
        for (int rr = 0; rr < 4; ++rr) {
          int n = n0 + 16*i + lg*4 + rr, m = m0 + 16*j + lr;
          float u = 0.5f*(Uf[n*SF + m] + Uf[m*SF + n]);
          float x = 2.0f*Xf[n*SF + m] - u;
          Xf[n*SF + m] = x;
          ushort hh, ll; bf16_split(x, hh, ll);
          Xh[n*SB + m] = hh; Xl[n*SB + m] = ll;
        }
    __syncthreads();   // X stable for next P1
  }

  // ---- output ----
#pragma unroll
  for (int i = 0; i < 16; ++i)
    invOut[(size_t)h*4096 + (size_t)r*64 + qq*16 + i] = Xf[r*SF + qq*16 + i];
}

// ---------------------------------------------------------------------------
// Leverage stage B: lev[h][s] = k_s^T inv_h k_s
// ---------------------------------------------------------------------------
__global__ __launch_bounds__(256) void levB_kernel(
    const float* __restrict__ Kmat, const float* __restrict__ invMat,
    float* __restrict__ lev) {
  int h = blockIdx.x;
  int s = blockIdx.y*256 + threadIdx.x;
  __shared__ __align__(16) float inv[64*64];
#pragma unroll
  for (int r = 0; r < 16; ++r)
    inv[threadIdx.x + 256*r] = invMat[(size_t)h*4096 + threadIdx.x + 256*r];
  __syncthreads();
  float kv[64];
  const float* kr = Kmat + ((size_t)h*S + s)*DH;
#pragma unroll
  for (int d4 = 0; d4 < 16; ++d4) {
    float4 t = ((const float4*)kr)[d4];
    kv[4*d4+0]=t.x; kv[4*d4+1]=t.y; kv[4*d4+2]=t.z; kv[4*d4+3]=t.w;
  }
  float acc = 0.f;
  for (int i = 0; i < 64; ++i) {
    float ti = 0.f;
    const float4* ir = (const float4*)(inv + i*64);
#pragma unroll
    for (int j4 = 0; j4 < 16; ++j4) {
      float4 iv = ir[j4];
      ti += iv.x*kv[4*j4] + iv.y*kv[4*j4+1] + iv.z*kv[4*j4+2] + iv.w*kv[4*j4+3];
    }
    acc += ti * kv[i];
  }
  lev[(size_t)h*S + s] = acc;
}

// ---------------------------------------------------------------------------
// Top-k via bitonic sort (value desc, index asc)
// ---------------------------------------------------------------------------
__global__ __launch_bounds__(256) void topk_kernel(
    const float* __restrict__ lev, int* __restrict__ idx_list) {
  int h = blockIdx.x, tid = threadIdx.x;
  __shared__ float sv[2048];
  __shared__ int   si[2048];
#pragma unroll
  for (int r = 0; r < 8; ++r) {
    int e = tid + 256*r;
    sv[e] = lev[(size_t)h*S + e];
    si[e] = e;
  }
  __syncthreads();
  for (int k = 2; k <= 2048; k <<= 1) {
    for (int j = k >> 1; j > 0; j >>= 1) {
      for (int r = 0; r < 8; ++r) {
        int i = tid + 256*r;
        int l = i ^ j;
        if (l > i) {
          float v1 = sv[i], v2 = sv[l];
          int   i1 = si[i], i2 = si[l];
          bool before = (v1 > v2) || (v1 == v2 && i1 < i2);
          bool dir = ((i & k) == 0);
          if (before != dir) { sv[i]=v2; sv[l]=v1; si[i]=i2; si[l]=i1; }
        }
      }
      __syncthreads();
    }
  }
#pragma unroll
  for (int r = 0; r < 2; ++r) {
    int t = tid + 256*r;
    idx_list[h*TOPK + t] = si[t];
  }
}

// ---------------------------------------------------------------------------
// Gather kept K/V rows -> bf16 split buffers.
// KCh/KCl: [bh][512][64]; VCth/VCtl: [bh][64][512] (transposed)
// ---------------------------------------------------------------------------
__global__ __launch_bounds__(256) void gather_kernel(
    const float* __restrict__ Kmat, const float* __restrict__ Vmat,
    const int* __restrict__ idx_list,
    ushort* __restrict__ KCh, ushort* __restrict__ KCl,
    ushort* __restrict__ VCth, ushort* __restrict__ VCtl) {
  int bh = blockIdx.x;        // 0..23
  int kc = blockIdx.y;        // 0..7
  int h = bh % H;
  __shared__ float vt[64][65];
  int tid = threadIdx.x;
  int kk = tid >> 2;           // key within chunk (0..63)
  int dq = (tid & 3) * 16;     // dh base (0,16,32,48)
  int j = kc*64 + kk;
  int srow = idx_list[h*TOPK + j];
  const float* kr = Kmat + ((size_t)bh*S + srow)*DH + dq;
  const float* vr = Vmat + ((size_t)bh*S + srow)*DH + dq;
  ushort hh[16], ll[16];
#pragma unroll
  for (int i = 0; i < 16; ++i) bf16_split(kr[i], hh[i], ll[i]);
  size_t kbase = ((size_t)bh*TOPK + j)*DH + dq;
  *(u16x8*)(KCh + kbase)     = *(u16x8*)&hh[0];
  *(u16x8*)(KCh + kbase + 8) = *(u16x8*)&hh[8];
  *(u16x8*)(KCl + kbase)     = *(u16x8*)&ll[0];
  *(u16x8*)(KCl + kbase + 8) = *(u16x8*)&ll[8];
#pragma unroll
  for (int i = 0; i < 16; ++i) vt[kk][dq + i] = vr[i];
  __syncthreads();
  int d  = tid >> 2;           // dh row (0..63)
  int kq = (tid & 3) * 16;     // key base within chunk
#pragma unroll
  for (int i = 0; i < 16; ++i) bf16_split(vt[kq + i][d], hh[i], ll[i]);
  size_t vbase = ((size_t)bh*DH + d)*TOPK + kc*64 + kq;
  *(u16x8*)(VCth + vbase)     = *(u16x8*)&hh[0];
  *(u16x8*)(VCth + vbase + 8) = *(u16x8*)&hh[8];
  *(u16x8*)(VCtl + vbase)     = *(u16x8*)&ll[0];
  *(u16x8*)(VCtl + vbase + 8) = *(u16x8*)&ll[8];
}

// ---------------------------------------------------------------------------
// MFMA attention, split-bf16: single pass, 4 waves/block, wave-private LDS.
// Epilogue writes CTX as bf16 hi/lo (feeds the MFMA output projection).
// ---------------------------------------------------------------------------
__global__ __launch_bounds__(256) void attn_kernel(
    const float* __restrict__ Q,
    const ushort* __restrict__ KCh, const ushort* __restrict__ KCl,
    const ushort* __restrict__ VCth, const ushort* __restrict__ VCtl,
    ushort* __restrict__ CTXh, ushort* __restrict__ CTXl) {
  __shared__ __align__(16) ushort SQh[4][16][88];
  __shared__ __align__(16) ushort SQl[4][16][88];
  int tid = threadIdx.x;
  int w = tid >> 6;
  int lane = tid & 63;
  int lr = lane & 15, lg = lane >> 4;
  int bh = blockIdx.x >> 5;
  int qt = blockIdx.x & 31;
  int qbase = qt*64 + w*16;
  int b = bh / H, h = bh % H;

  bf16x8 qh[2], ql[2];
#pragma unroll
  for (int ks = 0; ks < 2; ++ks) {
    const float* qp = Q + ((size_t)bh*S + qbase + lr)*DH + ks*32 + lg*8;
    float qv[8];
    *(float4*)&qv[0] = *(const float4*)qp;
    *(float4*)&qv[4] = *(const float4*)(qp + 4);
#pragma unroll
    for (int i = 0; i < 8; ++i) {
      ushort hh, lo; bf16_split(qv[i], hh, lo);
      qh[ks][i] = (short)hh; ql[ks][i] = (short)lo;
    }
  }

  f32x4 pacc[4] = {};
  float z_acc[4] = {};

  for (int c = 0; c < 8; ++c) {
    int keybase = c*64;
    f32x4 sacc[4] = {};
#pragma unroll
    for (int ks = 0; ks < 2; ++ks) {
#pragma unroll
      for (int f = 0; f < 4; ++f) {
        size_t koff = ((size_t)bh*TOPK + keybase + 16*f + lr)*DH + ks*32 + lg*8;
        bf16x8 kh = *(const bf16x8*)(KCh + koff);
        bf16x8 kl = *(const bf16x8*)(KCl + koff);
        sacc[f] = __builtin_amdgcn_mfma_f32_16x16x32_bf16(qh[ks], kh, sacc[f], 0, 0, 0);
        sacc[f] = __builtin_amdgcn_mfma_f32_16x16x32_bf16(qh[ks], kl, sacc[f], 0, 0, 0);
        sacc[f] = __builtin_amdgcn_mfma_f32_16x16x32_bf16(ql[ks], kh, sacc[f], 0, 0, 0);
      }
    }
    float zc[4] = {};
#pragma unroll
    for (int f = 0; f < 4; ++f) {
#pragma unroll
      for (int r = 0; r < 4; ++r) {
        float s = sacc[f][r];
        float sq = s*s;
        zc[r] += sq;
        ushort hh, lo; bf16_split(sq, hh, lo);
        SQh[w][lg*4 + r][16*f + lr] = hh;
        SQl[w][lg*4 + r][16*f + lr] = lo;
      }
    }
#pragma unroll
    for (int r = 0; r < 4; ++r) {
      float t = zc[r];
      t += __shfl_xor(t, 1);
      t += __shfl_xor(t, 2);
      t += __shfl_xor(t, 4);
      t += __shfl_xor(t, 8);
      z_acc[r] += t;
    }
#pragma unroll
    for (int ks = 0; ks < 2; ++ks) {
      bf16x8 ah = *(const bf16x8*)&SQh[w][lr][ks*32 + lg*8];
      bf16x8 al = *(const bf16x8*)&SQl[w][lr][ks*32 + lg*8];
#pragma unroll
      for (int f = 0; f < 4; ++f) {
        size_t voff = ((size_t)bh*DH + 16*f + lr)*TOPK + keybase + ks*32 + lg*8;
        bf16x8 vh = *(const bf16x8*)(VCth + voff);
        bf16x8 vl = *(const bf16x8*)(VCtl + voff);
        pacc[f] = __builtin_amdgcn_mfma_f32_16x16x32_bf16(ah, vh, pacc[f], 0, 0, 0);
        pacc[f] = __builtin_amdgcn_mfma_f32_16x16x32_bf16(ah, vl, pacc[f], 0, 0, 0);
        pacc[f] = __builtin_amdgcn_mfma_f32_16x16x32_bf16(al, vh, pacc[f], 0, 0, 0);
      }
    }
  }

  float zi[4];
#pragma unroll
  for (int r = 0; r < 4; ++r) zi[r] = 1.0f / (z_acc[r] + 1e-12f);
#pragma unroll
  for (int f = 0; f < 4; ++f) {
#pragma unroll
    for (int r = 0; r < 4; ++r) {
      int q = lg*4 + r;
      float val = pacc[f][r] * zi[r];
      ushort hh, lo; bf16_split(val, hh, lo);
      size_t o = ((size_t)b*S + qbase + q)*D + h*DH + 16*f + lr;
      CTXh[o] = hh; CTXl[o] = lo;
    }
  }
}

// ---------------------------------------------------------------------------
extern "C" void kernel_launch(void* const* d_in, const int* in_sizes, int n_in,
                              void* d_out, int out_size, void* d_ws, size_t ws_size,
                              hipStream_t stream) {
  const float* query = (const float*)d_in[0];
  const float* key   = (const float*)d_in[1];
  const float* value = (const float*)d_in[2];
  const float* Wq = (const float*)d_in[3];
  const float* bq = (const float*)d_in[4];
  const float* Wk = (const float*)d_in[5];
  const float* bk = (const float*)d_in[6];
  const float* Wv = (const float*)d_in[7];
  const float* bv = (const float*)d_in[8];
  const float* Wo = (const float*)d_in[9];
  const float* bo = (const float*)d_in[10];
  float* out = (float*)d_out;

  float* ws = (float*)d_ws;
  const size_t QKV = (size_t)B*H*S*DH;        // 3,145,728
  const size_t WSZ = (size_t)D*D;             // 589,824
  float* Qws   = ws;
  float* Kws   = Qws + QKV;
  float* Vws   = Kws + QKV;
  float* partials = Vws + QKV;                // 786,432
  float* ktkWs = partials + (size_t)H*16*4096;// H*4096
  float* invWs = ktkWs + (size_t)H*4096;      // H*4096
  float* levWs = invWs + (size_t)H*4096;
  ushort* Xh  = (ushort*)(levWs + (size_t)H*S);   // input split / later CTX
  ushort* Xl  = Xh + QKV;
  ushort* Wqh = Xl + QKV;  ushort* Wql = Wqh + WSZ;
  ushort* Wkh = Wql + WSZ; ushort* Wkl = Wkh + WSZ;
  ushort* Wvh = Wkl + WSZ; ushort* Wvl = Wvh + WSZ;
  ushort* Woh = Wvl + WSZ; ushort* Wol = Woh + WSZ;
  ushort* KCh  = Wol + WSZ;
  ushort* KCl  = KCh  + (size_t)B*H*TOPK*DH;
  ushort* VCth = KCl  + (size_t)B*H*TOPK*DH;
  ushort* VCtl = VCth + (size_t)B*H*TOPK*DH;
  int*   idxWs = (int*)(VCtl + (size_t)B*H*TOPK*DH);

  const int nW8 = (int)(WSZ/8), nX8 = (int)(QKV/8);
  splitw4_kernel<<<dim3(nW8/256, 1, 4), 256, 0, stream>>>(Wq, Wk, Wv, Wo, Wqh, nW8);

  dim3 pgrid(NROW/64, D/64);
  split_kernel<<<nX8/256, 256, 0, stream>>>(query, Xh, Xl, nX8);
  projmf_kernel<1,3><<<pgrid, 256, 0, stream>>>(Xh, Xl, Wqh, Wql, bq, Qws, 0.125f);
  split_kernel<<<nX8/256, 256, 0, stream>>>(key, Xh, Xl, nX8);
  projmf_kernel<1,4><<<pgrid, 256, 0, stream>>>(Xh, Xl, Wkh, Wkl, bk, Kws, 1.0f);
  split_kernel<<<nX8/256, 256, 0, stream>>>(value, Xh, Xl, nX8);
  projmf_kernel<1,3><<<pgrid, 256, 0, stream>>>(Xh, Xl, Wvh, Wvl, bv, Vws, 1.0f);

  levA1_kernel<<<dim3(H,16), 256, 0, stream>>>(Kws, partials);
  levA0_kernel<<<(H*4096)/256, 256, 0, stream>>>(partials, ktkWs);
  newton_inv_kernel<<<H, 256, 0, stream>>>(ktkWs, invWs);
  levB_kernel<<<dim3(H,8), 256, 0, stream>>>(Kws, invWs, levWs);
  topk_kernel<<<H, 256, 0, stream>>>(levWs, idxWs);

  gather_kernel<<<dim3(B*H, TOPK/64), 256, 0, stream>>>(
      Kws, Vws, idxWs, KCh, KCl, VCth, VCtl);

  // attn writes CTX split into Xh/Xl (input splits are dead by now)
  attn_kernel<<<B*H*(S/64), 256, 0, stream>>>(Qws, KCh, KCl, VCth, VCtl, Xh, Xl);

  projmf_kernel<0,3><<<pgrid, 256, 0, stream>>>(Xh, Xl, Woh, Wol, bo, out, 1.0f);
}

// Round 10
// 445.052 us; speedup vs baseline: 1.7723x; 1.1438x over previous
//
#include <hip/hip_runtime.h>

#define B 2
#define S 2048
#define D 768
#define H 12
#define DH 64
#define TOPK 512
#define NROW (B*S)   // 4096

typedef __attribute__((ext_vector_type(8))) short bf16x8;
typedef __attribute__((ext_vector_type(8))) ushort u16x8;
typedef __attribute__((ext_vector_type(4))) float f32x4;

// ---- bf16 split helpers (hi = RNE bf16 of x, lo = RNE bf16 of residual) ----
__device__ __forceinline__ ushort bf16_hi(float x) {
  union { float f; unsigned u; } v; v.f = x;
  unsigned r = v.u + 0x7fffu + ((v.u >> 16) & 1u);
  return (ushort)(r >> 16);
}
__device__ __forceinline__ float bf16_tof(ushort h) {
  union { float f; unsigned u; } v; v.u = ((unsigned)h) << 16; return v.f;
}
__device__ __forceinline__ void bf16_split(float x, ushort& h, ushort& l) {
  h = bf16_hi(x);
  l = bf16_hi(x - bf16_tof(h));
}

// ---------------------------------------------------------------------------
// Split fp32 tensor -> bf16 hi/lo buffers. 8 elements/thread.
// ---------------------------------------------------------------------------
__global__ __launch_bounds__(256) void split_kernel(
    const float* __restrict__ src, ushort* __restrict__ dh,
    ushort* __restrict__ dl, int n8) {
  int i = blockIdx.x*256 + threadIdx.x;
  if (i >= n8) return;
  float v[8];
  *(float4*)&v[0] = ((const float4*)src)[i*2];
  *(float4*)&v[4] = ((const float4*)src)[i*2+1];
  ushort hh[8], ll[8];
#pragma unroll
  for (int k = 0; k < 8; ++k) bf16_split(v[k], hh[k], ll[k]);
  ((u16x8*)dh)[i] = *(u16x8*)&hh[0];
  ((u16x8*)dl)[i] = *(u16x8*)&ll[0];
}

// ---------------------------------------------------------------------------
// Fused 4-way weight split (z = 0..3 selects Wq/Wk/Wv/Wo).
// ---------------------------------------------------------------------------
__global__ __launch_bounds__(256) void splitw4_kernel(
    const float* __restrict__ w0, const float* __restrict__ w1,
    const float* __restrict__ w2, const float* __restrict__ w3,
    ushort* __restrict__ dbase, int n8) {
  int z = blockIdx.z;
  const float* src = (z == 0) ? w0 : (z == 1) ? w1 : (z == 2) ? w2 : w3;
  ushort* dh = dbase + (size_t)z * 2u * (size_t)(D*D);
  ushort* dl = dh + (size_t)(D*D);
  int i = blockIdx.x*256 + threadIdx.x;
  if (i >= n8) return;
  float v[8];
  *(float4*)&v[0] = ((const float4*)src)[i*2];
  *(float4*)&v[4] = ((const float4*)src)[i*2+1];
  ushort hh[8], ll[8];
#pragma unroll
  for (int k = 0; k < 8; ++k) bf16_split(v[k], hh[k], ll[k]);
  ((u16x8*)dh)[i] = *(u16x8*)&hh[0];
  ((u16x8*)dl)[i] = *(u16x8*)&ll[0];
}

// ---------------------------------------------------------------------------
// Split-bf16 MFMA GEMM: C = A (N x 768) @ W^T + bias, * scale
// TERMS=4 (~fp32 exact; K-proj) / TERMS=3 (drops al*wl; smooth paths)
// MODE 0: C row-major fp32; MODE 1: scatter [b][h][s][dh] fp32;
// MODE 2: scatter [b][h][s][dh] as bf16 hi/lo (Ch/Cl)   [Q path]
// ---------------------------------------------------------------------------
template<int MODE, int TERMS>
__global__ __launch_bounds__(256) void projmf_kernel(
    const ushort* __restrict__ Ah, const ushort* __restrict__ Al,
    const ushort* __restrict__ Wh, const ushort* __restrict__ Wl,
    const float* __restrict__ bias, float* __restrict__ C,
    ushort* __restrict__ Ch, ushort* __restrict__ Cl, float scale) {
  int tid = threadIdx.x;
  int w = tid >> 6, lane = tid & 63;
  int lr = lane & 15, lg = lane >> 4;
  int n0 = blockIdx.x*64 + (w >> 1)*32;
  int m0 = blockIdx.y*64 + (w & 1)*32;
  f32x4 acc[2][2] = {};
  for (int ks = 0; ks < 24; ++ks) {
    int ko = ks*32 + lg*8;
    bf16x8 ah[2], al[2], wh[2], wl[2];
#pragma unroll
    for (int i = 0; i < 2; ++i) {
      size_t ao = (size_t)(n0 + 16*i + lr)*768 + ko;
      ah[i] = *(const bf16x8*)(Ah + ao);
      al[i] = *(const bf16x8*)(Al + ao);
      size_t wo = (size_t)(m0 + 16*i + lr)*768 + ko;
      wh[i] = *(const bf16x8*)(Wh + wo);
      wl[i] = *(const bf16x8*)(Wl + wo);
    }
#pragma unroll
    for (int i = 0; i < 2; ++i)
#pragma unroll
      for (int j = 0; j < 2; ++j) {
        acc[i][j] = __builtin_amdgcn_mfma_f32_16x16x32_bf16(ah[i], wh[j], acc[i][j], 0, 0, 0);
        acc[i][j] = __builtin_amdgcn_mfma_f32_16x16x32_bf16(ah[i], wl[j], acc[i][j], 0, 0, 0);
        acc[i][j] = __builtin_amdgcn_mfma_f32_16x16x32_bf16(al[i], wh[j], acc[i][j], 0, 0, 0);
        if (TERMS == 4)
          acc[i][j] = __builtin_amdgcn_mfma_f32_16x16x32_bf16(al[i], wl[j], acc[i][j], 0, 0, 0);
      }
  }
#pragma unroll
  for (int i = 0; i < 2; ++i)
#pragma unroll
    for (int j = 0; j < 2; ++j) {
      int m = m0 + 16*j + lr;
      float bv = bias[m];
#pragma unroll
      for (int r = 0; r < 4; ++r) {
        int n = n0 + 16*i + lg*4 + r;
        float val = (acc[i][j][r] + bv) * scale;
        if (MODE == 0) {
          C[(size_t)n*D + m] = val;
        } else {
          int b = n >> 11, s = n & 2047, hh = m >> 6, dh = m & 63;
          size_t o = (((size_t)b*H + hh)*S + s)*DH + dh;
          if (MODE == 1) {
            C[o] = val;
          } else {
            ushort vh, vl; bf16_split(val, vh, vl);
            Ch[o] = vh; Cl[o] = vl;
          }
        }
      }
    }
}

// ---------------------------------------------------------------------------
// Leverage stage A1: per-head partial KtK over 128-row chunks (batch 0 only)
// ---------------------------------------------------------------------------
__global__ __launch_bounds__(256) void levA1_kernel(
    const float* __restrict__ Kmat, float* __restrict__ partials) {
  int h = blockIdx.x, blk = blockIdx.y;
  __shared__ __align__(16) float ktile[128*64];
  int tid = threadIdx.x;
  const float* Kh = Kmat + ((size_t)h*S + (size_t)blk*128)*DH;
#pragma unroll
  for (int r = 0; r < 32; ++r) { int e = tid + 256*r; ktile[e] = Kh[e]; }
  __syncthreads();
  int j4 = tid & 15;
  float accf[4][4] = {};
  for (int ss = 0; ss < 128; ++ss) {
    float4 kj = ((const float4*)(ktile + ss*64))[j4];
#pragma unroll
    for (int r = 0; r < 4; ++r) {
      int i = (tid >> 4) + 16*r;
      float ki = ktile[ss*64 + i];
      accf[r][0] += ki*kj.x; accf[r][1] += ki*kj.y;
      accf[r][2] += ki*kj.z; accf[r][3] += ki*kj.w;
    }
  }
  size_t base = ((size_t)h*16 + blk)*4096;
#pragma unroll
  for (int r = 0; r < 4; ++r) {
    int i = (tid >> 4) + 16*r;
#pragma unroll
    for (int c = 0; c < 4; ++c)
      partials[base + (size_t)i*64 + j4*4 + c] = accf[r][c];
  }
}

// ---------------------------------------------------------------------------
// Leverage stage A0-reduce: fp64 sum of the 16 partials + damping.
// ---------------------------------------------------------------------------
__global__ __launch_bounds__(256) void levA0_kernel(
    const float* __restrict__ partials, float* __restrict__ KtK) {
  int g = blockIdx.x*256 + threadIdx.x;        // 0 .. H*4096-1
  int h = g >> 12, e = g & 4095;
  const float* pb = partials + (size_t)h*65536 + e;
  double t = 0.0;
#pragma unroll
  for (int p = 0; p < 16; ++p) t += (double)pb[(size_t)p*4096];
  if ((e >> 6) == (e & 63)) t += 1e-6;
  KtK[g] = (float)t;
}

// ---------------------------------------------------------------------------
// Newton-iteration inverse via MFMA. One block (256 thr, 4 waves) per head.
// X0 = I/||A||inf; 12 iters of X' = 2X - sym(X A X^T). X stays bitwise
// symmetric. Epilogue also emits bf16 hi/lo splits of inv for levB's MFMA.
// ---------------------------------------------------------------------------
__global__ __launch_bounds__(256) void newton_inv_kernel(
    const float* __restrict__ KtK, float* __restrict__ invOut,
    ushort* __restrict__ invH, ushort* __restrict__ invL) {
  const int SF = 68;   // fp32 LDS row stride
  const int SB = 72;   // bf16 LDS row stride
  __shared__ float Xf[64*SF];
  __shared__ float Uf[64*SF];
  __shared__ __align__(16) ushort Ah[64*SB], Al[64*SB];
  __shared__ __align__(16) ushort Xh[64*SB], Xl[64*SB];
  __shared__ __align__(16) ushort Th[64*SB], Tl[64*SB];
  __shared__ float rsum[64];
  __shared__ float csh;
  int h = blockIdx.x, tid = threadIdx.x;
  int w = tid >> 6, lane = tid & 63;
  int lr = lane & 15, lg = lane >> 4;
  int r = tid >> 2, qq = tid & 3;

  float s = 0.f;
  {
    const float* src = KtK + (size_t)h*4096 + (size_t)r*64 + qq*16;
#pragma unroll
    for (int i = 0; i < 16; ++i) {
      float a = src[i];
      s += fabsf(a);
      ushort hh, ll; bf16_split(a, hh, ll);
      Ah[r*SB + qq*16 + i] = hh; Al[r*SB + qq*16 + i] = ll;
    }
    s += __shfl_xor(s, 1);
    s += __shfl_xor(s, 2);
    if (qq == 0) rsum[r] = s;
  }
  __syncthreads();
  if (tid < 64) {
    float m = rsum[tid];
#pragma unroll
    for (int o = 32; o; o >>= 1) m = fmaxf(m, __shfl_xor(m, o));
    if (tid == 0) csh = 1.0f / m;
  }
  __syncthreads();
  float c = csh;
#pragma unroll
  for (int i = 0; i < 16; ++i) {
    int e = qq*16 + i;
    float x0 = (e == r) ? c : 0.0f;
    Xf[r*SF + e] = x0;
    ushort hh, ll; bf16_split(x0, hh, ll);
    Xh[r*SB + e] = hh; Xl[r*SB + e] = ll;
  }
  __syncthreads();

  int n0 = (w >> 1)*32, m0 = (w & 1)*32;
  for (int it = 0; it < 12; ++it) {
    // P1: T' = X * A^T
    {
      f32x4 acc[2][2] = {};
#pragma unroll
      for (int ks = 0; ks < 2; ++ks) {
        bf16x8 pah[2], pal[2], pbh[2], pbl[2];
#pragma unroll
        for (int i = 0; i < 2; ++i) {
          int ao = (n0 + 16*i + lr)*SB + ks*32 + lg*8;
          pah[i] = *(const bf16x8*)&Xh[ao]; pal[i] = *(const bf16x8*)&Xl[ao];
          int bo = (m0 + 16*i + lr)*SB + ks*32 + lg*8;
          pbh[i] = *(const bf16x8*)&Ah[bo]; pbl[i] = *(const bf16x8*)&Al[bo];
        }
#pragma unroll
        for (int i = 0; i < 2; ++i)
#pragma unroll
          for (int j = 0; j < 2; ++j) {
            acc[i][j] = __builtin_amdgcn_mfma_f32_16x16x32_bf16(pah[i], pbh[j], acc[i][j], 0, 0, 0);
            acc[i][j] = __builtin_amdgcn_mfma_f32_16x16x32_bf16(pah[i], pbl[j], acc[i][j], 0, 0, 0);
            acc[i][j] = __builtin_amdgcn_mfma_f32_16x16x32_bf16(pal[i], pbh[j], acc[i][j], 0, 0, 0);
            acc[i][j] = __builtin_amdgcn_mfma_f32_16x16x32_bf16(pal[i], pbl[j], acc[i][j], 0, 0, 0);
          }
      }
#pragma unroll
      for (int i = 0; i < 2; ++i)
#pragma unroll
        for (int j = 0; j < 2; ++j)
#pragma unroll
          for (int rr = 0; rr < 4; ++rr) {
            int n = n0 + 16*i + lg*4 + rr, m = m0 + 16*j + lr;
            ushort hh, ll; bf16_split(acc[i][j][rr], hh, ll);
            Th[n*SB + m] = hh; Tl[n*SB + m] = ll;
          }
    }
    __syncthreads();
    // P2: U = X * T'^T
    {
      f32x4 acc[2][2] = {};
#pragma unroll
      for (int ks = 0; ks < 2; ++ks) {
        bf16x8 pah[2], pal[2], pbh[2], pbl[2];
#pragma unroll
        for (int i = 0; i < 2; ++i) {
          int ao = (n0 + 16*i + lr)*SB + ks*32 + lg*8;
          pah[i] = *(const bf16x8*)&Xh[ao]; pal[i] = *(const bf16x8*)&Xl[ao];
          int bo = (m0 + 16*i + lr)*SB + ks*32 + lg*8;
          pbh[i] = *(const bf16x8*)&Th[bo]; pbl[i] = *(const bf16x8*)&Tl[bo];
        }
#pragma unroll
        for (int i = 0; i < 2; ++i)
#pragma unroll
          for (int j = 0; j < 2; ++j) {
            acc[i][j] = __builtin_amdgcn_mfma_f32_16x16x32_bf16(pah[i], pbh[j], acc[i][j], 0, 0, 0);
            acc[i][j] = __builtin_amdgcn_mfma_f32_16x16x32_bf16(pah[i], pbl[j], acc[i][j], 0, 0, 0);
            acc[i][j] = __builtin_amdgcn_mfma_f32_16x16x32_bf16(pal[i], pbh[j], acc[i][j], 0, 0, 0);
            acc[i][j] = __builtin_amdgcn_mfma_f32_16x16x32_bf16(pal[i], pbl[j], acc[i][j], 0, 0, 0);
          }
      }
#pragma unroll
      for (int i = 0; i < 2; ++i)
#pragma unroll
        for (int j = 0; j < 2; ++j)
#pragma unroll
          for (int rr = 0; rr < 4; ++rr) {
            int n = n0 + 16*i + lg*4 + rr, m = m0 + 16*j + lr;
            Uf[n*SF + m] = acc[i][j][rr];
          }
    }
    __syncthreads();
    // P3: X' = 2X - 0.5(U + U^T)
#pragma unroll
    for (int i = 0; i < 2; ++i)
#pragma unroll
      for (int j = 0; j < 2; ++j)
#pragma unroll
        for (int rr = 0; rr < 4; ++rr) {
          int n = n0 + 16*i + lg*4 + rr, m = m0 + 16*j + lr;
          float u = 0.5f*(Uf[n*SF + m] + Uf[m*SF + n]);
          float x = 2.0f*Xf[n*SF + m] - u;
          Xf[n*SF + m] = x;
          ushort hh, ll; bf16_split(x, hh, ll);
          Xh[n*SB + m] = hh; Xl[n*SB + m] = ll;
        }
    __syncthreads();
  }

#pragma unroll
  for (int i = 0; i < 16; ++i) {
    float x = Xf[r*SF + qq*16 + i];
    size_t o = (size_t)h*4096 + (size_t)r*64 + qq*16 + i;
    invOut[o] = x;
    ushort hh, ll; bf16_split(x, hh, ll);
    invH[o] = hh; invL[o] = ll;
  }
}

// ---------------------------------------------------------------------------
// Leverage stage B via MFMA: T = K @ inv^T (inv symmetric -> = K @ inv),
// lev[s] = sum_j T[s][j] * K[s][j]. 4-term split-bf16 ~ fp32 exact.
// Grid (S/64, H); block 256 = 4 waves x 16 rows.
// ---------------------------------------------------------------------------
__global__ __launch_bounds__(256) void levB_kernel(
    const float* __restrict__ Kmat,
    const ushort* __restrict__ Kbh, const ushort* __restrict__ Kbl,
    const ushort* __restrict__ invH, const ushort* __restrict__ invL,
    float* __restrict__ lev) {
  int h = blockIdx.y;
  int tid = threadIdx.x;
  int w = tid >> 6, lane = tid & 63;
  int lr = lane & 15, lg = lane >> 4;
  int qbase = blockIdx.x*64 + w*16;
  f32x4 sacc[4] = {};
#pragma unroll
  for (int ks = 0; ks < 2; ++ks) {
    size_t ko = ((size_t)h*S + qbase + lr)*DH + ks*32 + lg*8;
    bf16x8 kh = *(const bf16x8*)(Kbh + ko);
    bf16x8 kl = *(const bf16x8*)(Kbl + ko);
#pragma unroll
    for (int f = 0; f < 4; ++f) {
      size_t io = (size_t)h*4096 + (size_t)(16*f + lr)*64 + ks*32 + lg*8;
      bf16x8 ih = *(const bf16x8*)(invH + io);
      bf16x8 il = *(const bf16x8*)(invL + io);
      sacc[f] = __builtin_amdgcn_mfma_f32_16x16x32_bf16(kh, ih, sacc[f], 0, 0, 0);
      sacc[f] = __builtin_amdgcn_mfma_f32_16x16x32_bf16(kh, il, sacc[f], 0, 0, 0);
      sacc[f] = __builtin_amdgcn_mfma_f32_16x16x32_bf16(kl, ih, sacc[f], 0, 0, 0);
      sacc[f] = __builtin_amdgcn_mfma_f32_16x16x32_bf16(kl, il, sacc[f], 0, 0, 0);
    }
  }
  float zc[4] = {};
#pragma unroll
  for (int f = 0; f < 4; ++f)
#pragma unroll
    for (int r = 0; r < 4; ++r) {
      float kv = Kmat[((size_t)h*S + qbase + lg*4 + r)*DH + 16*f + lr];
      zc[r] = fmaf(sacc[f][r], kv, zc[r]);
    }
#pragma unroll
  for (int r = 0; r < 4; ++r) {
    float t = zc[r];
    t += __shfl_xor(t, 1);
    t += __shfl_xor(t, 2);
    t += __shfl_xor(t, 4);
    t += __shfl_xor(t, 8);
    if (lr == 0) lev[(size_t)h*S + qbase + lg*4 + r] = t;
  }
}

// ---------------------------------------------------------------------------
// Top-k via bitonic sort (value desc, index asc)
// ---------------------------------------------------------------------------
__global__ __launch_bounds__(256) void topk_kernel(
    const float* __restrict__ lev, int* __restrict__ idx_list) {
  int h = blockIdx.x, tid = threadIdx.x;
  __shared__ float sv[2048];
  __shared__ int   si[2048];
#pragma unroll
  for (int r = 0; r < 8; ++r) {
    int e = tid + 256*r;
    sv[e] = lev[(size_t)h*S + e];
    si[e] = e;
  }
  __syncthreads();
  for (int k = 2; k <= 2048; k <<= 1) {
    for (int j = k >> 1; j > 0; j >>= 1) {
      for (int r = 0; r < 8; ++r) {
        int i = tid + 256*r;
        int l = i ^ j;
        if (l > i) {
          float v1 = sv[i], v2 = sv[l];
          int   i1 = si[i], i2 = si[l];
          bool before = (v1 > v2) || (v1 == v2 && i1 < i2);
          bool dir = ((i & k) == 0);
          if (before != dir) { sv[i]=v2; sv[l]=v1; si[i]=i2; si[l]=i1; }
        }
      }
      __syncthreads();
    }
  }
#pragma unroll
  for (int r = 0; r < 2; ++r) {
    int t = tid + 256*r;
    idx_list[h*TOPK + t] = si[t];
  }
}

// ---------------------------------------------------------------------------
// Gather kept K/V rows -> bf16 split buffers.
// KCh/KCl: [bh][512][64]; VCth/VCtl: [bh][64][512] (transposed)
// ---------------------------------------------------------------------------
__global__ __launch_bounds__(256) void gather_kernel(
    const float* __restrict__ Kmat, const float* __restrict__ Vmat,
    const int* __restrict__ idx_list,
    ushort* __restrict__ KCh, ushort* __restrict__ KCl,
    ushort* __restrict__ VCth, ushort* __restrict__ VCtl) {
  int bh = blockIdx.x;        // 0..23
  int kc = blockIdx.y;        // 0..7
  int h = bh % H;
  __shared__ float vt[64][65];
  int tid = threadIdx.x;
  int kk = tid >> 2;           // key within chunk (0..63)
  int dq = (tid & 3) * 16;     // dh base (0,16,32,48)
  int j = kc*64 + kk;
  int srow = idx_list[h*TOPK + j];
  const float* kr = Kmat + ((size_t)bh*S + srow)*DH + dq;
  const float* vr = Vmat + ((size_t)bh*S + srow)*DH + dq;
  ushort hh[16], ll[16];
#pragma unroll
  for (int i = 0; i < 16; ++i) bf16_split(kr[i], hh[i], ll[i]);
  size_t kbase = ((size_t)bh*TOPK + j)*DH + dq;
  *(u16x8*)(KCh + kbase)     = *(u16x8*)&hh[0];
  *(u16x8*)(KCh + kbase + 8) = *(u16x8*)&hh[8];
  *(u16x8*)(KCl + kbase)     = *(u16x8*)&ll[0];
  *(u16x8*)(KCl + kbase + 8) = *(u16x8*)&ll[8];
#pragma unroll
  for (int i = 0; i < 16; ++i) vt[kk][dq + i] = vr[i];
  __syncthreads();
  int d  = tid >> 2;           // dh row (0..63)
  int kq = (tid & 3) * 16;     // key base within chunk
#pragma unroll
  for (int i = 0; i < 16; ++i) bf16_split(vt[kq + i][d], hh[i], ll[i]);
  size_t vbase = ((size_t)bh*DH + d)*TOPK + kc*64 + kq;
  *(u16x8*)(VCth + vbase)     = *(u16x8*)&hh[0];
  *(u16x8*)(VCth + vbase + 8) = *(u16x8*)&hh[8];
  *(u16x8*)(VCtl + vbase)     = *(u16x8*)&ll[0];
  *(u16x8*)(VCtl + vbase + 8) = *(u16x8*)&ll[8];
}

// ---------------------------------------------------------------------------
// MFMA attention, split-bf16, v2: K/V chunk tiles staged in LDS (shared by
// all 4 waves; padded row stride 72 ushort -> 2-way bank aliasing = free on
// both ds_write and ds_read), XCD-grouped block swizzle (each XCD owns 3 bh
// -> compact KV is L2-resident), Q read directly as bf16 hi/lo fragments.
// ---------------------------------------------------------------------------
__global__ __launch_bounds__(256) void attn_kernel(
    const ushort* __restrict__ Qh_g, const ushort* __restrict__ Ql_g,
    const ushort* __restrict__ KCh, const ushort* __restrict__ KCl,
    const ushort* __restrict__ VCth, const ushort* __restrict__ VCtl,
    ushort* __restrict__ CTXh, ushort* __restrict__ CTXl) {
  const int ST = 72;   // tile row stride (ushorts)
  __shared__ __align__(16) ushort Kt_h[64*ST], Kt_l[64*ST];
  __shared__ __align__(16) ushort Vt_h[64*ST], Vt_l[64*ST];
  __shared__ __align__(16) ushort SQh[4][16][88];
  __shared__ __align__(16) ushort SQl[4][16][88];
  int tid = threadIdx.x;
  int w = tid >> 6;
  int lane = tid & 63;
  int lr = lane & 15, lg = lane >> 4;
  // XCD-grouping swizzle: 768 blocks = 8 xcd x (3 bh x 32 qt)
  int bid = blockIdx.x;
  int xcd = bid & 7, jj = bid >> 3;
  int bh = xcd*3 + (jj >> 5);
  int qt = jj & 31;
  int qbase = qt*64 + w*16;
  int b = bh / H, h = bh % H;

  bf16x8 qh[2], ql[2];
#pragma unroll
  for (int ks = 0; ks < 2; ++ks) {
    size_t qo = ((size_t)bh*S + qbase + lr)*DH + ks*32 + lg*8;
    qh[ks] = *(const bf16x8*)(Qh_g + qo);
    ql[ks] = *(const bf16x8*)(Ql_g + qo);
  }

  f32x4 pacc[4] = {};
  float z_acc[4] = {};
  int srow = tid >> 2;          // staging: row 0..63
  int sseg = (tid & 3) * 16;    // 16-ushort segment within row

  for (int c = 0; c < 8; ++c) {
    int keybase = c*64;
    // ---- stage K/V chunk tiles into LDS (all 256 threads) ----
    {
      size_t kg = ((size_t)bh*TOPK + keybase + srow)*DH + sseg;
      size_t vg = ((size_t)bh*DH + srow)*TOPK + keybase + sseg;
      u16x8 a0 = *(const u16x8*)(KCh + kg);
      u16x8 a1 = *(const u16x8*)(KCh + kg + 8);
      u16x8 b0 = *(const u16x8*)(KCl + kg);
      u16x8 b1 = *(const u16x8*)(KCl + kg + 8);
      u16x8 c0 = *(const u16x8*)(VCth + vg);
      u16x8 c1 = *(const u16x8*)(VCth + vg + 8);
      u16x8 d0 = *(const u16x8*)(VCtl + vg);
      u16x8 d1 = *(const u16x8*)(VCtl + vg + 8);
      int lo = srow*ST + sseg;
      *(u16x8*)&Kt_h[lo] = a0; *(u16x8*)&Kt_h[lo + 8] = a1;
      *(u16x8*)&Kt_l[lo] = b0; *(u16x8*)&Kt_l[lo + 8] = b1;
      *(u16x8*)&Vt_h[lo] = c0; *(u16x8*)&Vt_h[lo + 8] = c1;
      *(u16x8*)&Vt_l[lo] = d0; *(u16x8*)&Vt_l[lo + 8] = d1;
    }
    __syncthreads();
    // ---- scores ----
    f32x4 sacc[4] = {};
#pragma unroll
    for (int ks = 0; ks < 2; ++ks) {
#pragma unroll
      for (int f = 0; f < 4; ++f) {
        int ko = (16*f + lr)*ST + ks*32 + lg*8;
        bf16x8 kh = *(const bf16x8*)&Kt_h[ko];
        bf16x8 kl = *(const bf16x8*)&Kt_l[ko];
        sacc[f] = __builtin_amdgcn_mfma_f32_16x16x32_bf16(qh[ks], kh, sacc[f], 0, 0, 0);
        sacc[f] = __builtin_amdgcn_mfma_f32_16x16x32_bf16(qh[ks], kl, sacc[f], 0, 0, 0);
        sacc[f] = __builtin_amdgcn_mfma_f32_16x16x32_bf16(ql[ks], kh, sacc[f], 0, 0, 0);
      }
    }
    // ---- square, z partials, sq -> wave-private LDS ----
    float zc[4] = {};
#pragma unroll
    for (int f = 0; f < 4; ++f) {
#pragma unroll
      for (int r = 0; r < 4; ++r) {
        float s = sacc[f][r];
        float sq = s*s;
        zc[r] += sq;
        ushort hh, lo; bf16_split(sq, hh, lo);
        SQh[w][lg*4 + r][16*f + lr] = hh;
        SQl[w][lg*4 + r][16*f + lr] = lo;
      }
    }
#pragma unroll
    for (int r = 0; r < 4; ++r) {
      float t = zc[r];
      t += __shfl_xor(t, 1);
      t += __shfl_xor(t, 2);
      t += __shfl_xor(t, 4);
      t += __shfl_xor(t, 8);
      z_acc[r] += t;
    }
    // ---- PV ----
#pragma unroll
    for (int ks = 0; ks < 2; ++ks) {
      bf16x8 ah = *(const bf16x8*)&SQh[w][lr][ks*32 + lg*8];
      bf16x8 al = *(const bf16x8*)&SQl[w][lr][ks*32 + lg*8];
#pragma unroll
      for (int f = 0; f < 4; ++f) {
        int vo = (16*f + lr)*ST + ks*32 + lg*8;
        bf16x8 vh = *(const bf16x8*)&Vt_h[vo];
        bf16x8 vl = *(const bf16x8*)&Vt_l[vo];
        pacc[f] = __builtin_amdgcn_mfma_f32_16x16x32_bf16(ah, vh, pacc[f], 0, 0, 0);
        pacc[f] = __builtin_amdgcn_mfma_f32_16x16x32_bf16(ah, vl, pacc[f], 0, 0, 0);
        pacc[f] = __builtin_amdgcn_mfma_f32_16x16x32_bf16(al, vh, pacc[f], 0, 0, 0);
      }
    }
    __syncthreads();   // tile reads done before next stage overwrites
  }

  float zi[4];
#pragma unroll
  for (int r = 0; r < 4; ++r) zi[r] = 1.0f / (z_acc[r] + 1e-12f);
#pragma unroll
  for (int f = 0; f < 4; ++f) {
#pragma unroll
    for (int r = 0; r < 4; ++r) {
      int q = lg*4 + r;
      float val = pacc[f][r] * zi[r];
      ushort hh, lo; bf16_split(val, hh, lo);
      size_t o = ((size_t)b*S + qbase + q)*D + h*DH + 16*f + lr;
      CTXh[o] = hh; CTXl[o] = lo;
    }
  }
}

// ---------------------------------------------------------------------------
extern "C" void kernel_launch(void* const* d_in, const int* in_sizes, int n_in,
                              void* d_out, int out_size, void* d_ws, size_t ws_size,
                              hipStream_t stream) {
  const float* query = (const float*)d_in[0];
  const float* key   = (const float*)d_in[1];
  const float* value = (const float*)d_in[2];
  const float* Wq = (const float*)d_in[3];
  const float* bq = (const float*)d_in[4];
  const float* Wk = (const float*)d_in[5];
  const float* bk = (const float*)d_in[6];
  const float* Wv = (const float*)d_in[7];
  const float* bv = (const float*)d_in[8];
  const float* Wo = (const float*)d_in[9];
  const float* bo = (const float*)d_in[10];
  float* out = (float*)d_out;

  float* ws = (float*)d_ws;
  const size_t QKV = (size_t)B*H*S*DH;        // 3,145,728
  const size_t WSZ = (size_t)D*D;             // 589,824
  const size_t KB0 = (size_t)H*S*DH;          // 1,572,864 (batch-0 K)
  ushort* Qh = (ushort*)ws;                   // Q split (replaces fp32 Q)
  ushort* Ql = Qh + QKV;
  float* Kws   = (float*)(Ql + QKV);
  float* Vws   = Kws + QKV;
  float* partials = Vws + QKV;                // 786,432
  float* ktkWs = partials + (size_t)H*16*4096;// H*4096
  float* invWs = ktkWs + (size_t)H*4096;      // H*4096
  float* levWs = invWs + (size_t)H*4096;
  ushort* Xh  = (ushort*)(levWs + (size_t)H*S);   // input split / later CTX
  ushort* Xl  = Xh + QKV;
  ushort* Wqh = Xl + QKV;  ushort* Wql = Wqh + WSZ;
  ushort* Wkh = Wql + WSZ; ushort* Wkl = Wkh + WSZ;
  ushort* Wvh = Wkl + WSZ; ushort* Wvl = Wvh + WSZ;
  ushort* Woh = Wvl + WSZ; ushort* Wol = Woh + WSZ;
  ushort* KCh  = Wol + WSZ;
  ushort* KCl  = KCh  + (size_t)B*H*TOPK*DH;
  ushort* VCth = KCl  + (size_t)B*H*TOPK*DH;
  ushort* VCtl = VCth + (size_t)B*H*TOPK*DH;
  ushort* Kbh  = VCtl + (size_t)B*H*TOPK*DH;  // batch-0 K split
  ushort* Kbl  = Kbh + KB0;
  ushort* invH = Kbl + KB0;                   // inv split
  ushort* invL = invH + (size_t)H*4096;
  int*   idxWs = (int*)(invL + (size_t)H*4096);

  const int nW8 = (int)(WSZ/8), nX8 = (int)(QKV/8);
  splitw4_kernel<<<dim3(nW8/256, 1, 4), 256, 0, stream>>>(Wq, Wk, Wv, Wo, Wqh, nW8);

  dim3 pgrid(NROW/64, D/64);
  split_kernel<<<nX8/256, 256, 0, stream>>>(query, Xh, Xl, nX8);
  projmf_kernel<2,3><<<pgrid, 256, 0, stream>>>(Xh, Xl, Wqh, Wql, bq, nullptr, Qh, Ql, 0.125f);
  split_kernel<<<nX8/256, 256, 0, stream>>>(key, Xh, Xl, nX8);
  projmf_kernel<1,4><<<pgrid, 256, 0, stream>>>(Xh, Xl, Wkh, Wkl, bk, Kws, nullptr, nullptr, 1.0f);
  split_kernel<<<nX8/256, 256, 0, stream>>>(value, Xh, Xl, nX8);
  projmf_kernel<1,3><<<pgrid, 256, 0, stream>>>(Xh, Xl, Wvh, Wvl, bv, Vws, nullptr, nullptr, 1.0f);

  levA1_kernel<<<dim3(H,16), 256, 0, stream>>>(Kws, partials);
  levA0_kernel<<<(H*4096)/256, 256, 0, stream>>>(partials, ktkWs);
  newton_inv_kernel<<<H, 256, 0, stream>>>(ktkWs, invWs, invH, invL);
  split_kernel<<<(int)(KB0/8)/256, 256, 0, stream>>>(Kws, Kbh, Kbl, (int)(KB0/8));
  levB_kernel<<<dim3(S/64, H), 256, 0, stream>>>(Kws, Kbh, Kbl, invH, invL, levWs);
  topk_kernel<<<H, 256, 0, stream>>>(levWs, idxWs);

  gather_kernel<<<dim3(B*H, TOPK/64), 256, 0, stream>>>(
      Kws, Vws, idxWs, KCh, KCl, VCth, VCtl);

  // attn writes CTX split into Xh/Xl (input splits are dead by now)
  attn_kernel<<<B*H*(S/64), 256, 0, stream>>>(Qh, Ql, KCh, KCl, VCth, VCtl, Xh, Xl);

  projmf_kernel<0,3><<<pgrid, 256, 0, stream>>>(Xh, Xl, Woh, Wol, bo, out, nullptr, nullptr, 1.0f);
}

// Round 11
// 249.213 us; speedup vs baseline: 3.1651x; 1.7858x over previous
//
#include <hip/hip_runtime.h>

#define B 2
#define S 2048
#define D 768
#define H 12
#define DH 64
#define TOPK 512
#define NROW (B*S)   // 4096

typedef __attribute__((ext_vector_type(8))) short bf16x8;
typedef __attribute__((ext_vector_type(8))) ushort u16x8;
typedef __attribute__((ext_vector_type(4))) float f32x4;

#define QKVSZ ((size_t)B*H*S*DH)   // 3,145,728
#define WSZC  ((size_t)D*D)        // 589,824

// ---- bf16 split helpers (hi = RNE bf16 of x, lo = RNE bf16 of residual) ----
__device__ __forceinline__ ushort bf16_hi(float x) {
  union { float f; unsigned u; } v; v.f = x;
  unsigned r = v.u + 0x7fffu + ((v.u >> 16) & 1u);
  return (ushort)(r >> 16);
}
__device__ __forceinline__ float bf16_tof(ushort h) {
  union { float f; unsigned u; } v; v.u = ((unsigned)h) << 16; return v.f;
}
__device__ __forceinline__ void bf16_split(float x, ushort& h, ushort& l) {
  h = bf16_hi(x);
  l = bf16_hi(x - bf16_tof(h));
}

// ---------------------------------------------------------------------------
// Batched input split: z = 0/1/2 selects query/key/value -> [z][QKV] slabs.
// ---------------------------------------------------------------------------
__global__ __launch_bounds__(256) void split3_kernel(
    const float* __restrict__ s0, const float* __restrict__ s1,
    const float* __restrict__ s2, ushort* __restrict__ dhB,
    ushort* __restrict__ dlB, int n8) {
  int z = blockIdx.z;
  const float* src = (z == 0) ? s0 : (z == 1) ? s1 : s2;
  ushort* dh = dhB + (size_t)z * QKVSZ;
  ushort* dl = dlB + (size_t)z * QKVSZ;
  int i = blockIdx.x*256 + threadIdx.x;
  if (i >= n8) return;
  float v[8];
  *(float4*)&v[0] = ((const float4*)src)[i*2];
  *(float4*)&v[4] = ((const float4*)src)[i*2+1];
  ushort hh[8], ll[8];
#pragma unroll
  for (int k = 0; k < 8; ++k) bf16_split(v[k], hh[k], ll[k]);
  ((u16x8*)dh)[i] = *(u16x8*)&hh[0];
  ((u16x8*)dl)[i] = *(u16x8*)&ll[0];
}

// ---------------------------------------------------------------------------
// Fused 4-way weight split (z = 0..3 selects Wq/Wk/Wv/Wo).
// ---------------------------------------------------------------------------
__global__ __launch_bounds__(256) void splitw4_kernel(
    const float* __restrict__ w0, const float* __restrict__ w1,
    const float* __restrict__ w2, const float* __restrict__ w3,
    ushort* __restrict__ dbase, int n8) {
  int z = blockIdx.z;
  const float* src = (z == 0) ? w0 : (z == 1) ? w1 : (z == 2) ? w2 : w3;
  ushort* dh = dbase + (size_t)z * 2u * WSZC;
  ushort* dl = dh + WSZC;
  int i = blockIdx.x*256 + threadIdx.x;
  if (i >= n8) return;
  float v[8];
  *(float4*)&v[0] = ((const float4*)src)[i*2];
  *(float4*)&v[4] = ((const float4*)src)[i*2+1];
  ushort hh[8], ll[8];
#pragma unroll
  for (int k = 0; k < 8; ++k) bf16_split(v[k], hh[k], ll[k]);
  ((u16x8*)dh)[i] = *(u16x8*)&hh[0];
  ((u16x8*)dl)[i] = *(u16x8*)&ll[0];
}

// ---------------------------------------------------------------------------
// projmf v2: LDS-staged split-bf16 MFMA GEMM, 4-term (~fp32 exact).
// Tile 64x64, BK=64, 12 K-steps, 4 waves (each 32x32 = 2x2 fragments).
// LDS: 4 tiles @ stride 72 ushorts (2-way bank aliasing = free, same
// pattern as the working attn staging). 2 barriers/K-step, single buffer.
// PATH 0 (QKV batched, z=blockIdx.z): z=0 Q -> bf16 hi/lo scatter (*1/8);
//   z=1 K -> fp32 scatter + batch-0 bf16 splits (for levB); z=2 V -> fp32.
// PATH 1 (O-proj, z=3): row-major fp32 out.
// ---------------------------------------------------------------------------
template<int PATH>
__global__ __launch_bounds__(256) void projmf2_kernel(
    const ushort* __restrict__ Ah_base, const ushort* __restrict__ Al_base,
    const ushort* __restrict__ Wbase,
    const float* __restrict__ bq, const float* __restrict__ bk,
    const float* __restrict__ bv, const float* __restrict__ bo,
    float* __restrict__ Kout, float* __restrict__ Vout,
    ushort* __restrict__ Qh, ushort* __restrict__ Ql,
    ushort* __restrict__ Kbh, ushort* __restrict__ Kbl,
    float* __restrict__ Oout) {
  const int ST = 72;
  __shared__ __align__(16) ushort Ash[64*ST], Asl[64*ST];
  __shared__ __align__(16) ushort Wsh[64*ST], Wsl[64*ST];
  int tid = threadIdx.x;
  int w = tid >> 6, lane = tid & 63;
  int lr = lane & 15, lg = lane >> 4;
  int z = (PATH == 0) ? blockIdx.z : 3;
  const ushort* Ah = Ah_base + (PATH == 0 ? (size_t)z * QKVSZ : 0);
  const ushort* Al = Al_base + (PATH == 0 ? (size_t)z * QKVSZ : 0);
  const ushort* Wh = Wbase + (size_t)z * 2u * WSZC;
  const ushort* Wl = Wh + WSZC;
  const float* bias = (PATH == 1) ? bo : (z == 0 ? bq : (z == 1 ? bk : bv));
  float scale = (PATH == 0 && z == 0) ? 0.125f : 1.0f;
  int n0 = blockIdx.x*64, m0 = blockIdx.y*64;
  int wr0 = (w >> 1)*32, wc0 = (w & 1)*32;   // wave tile offsets within block
  int srow = tid >> 2, sseg = (tid & 3)*16;  // staging map (row, 16-ushort seg)
  f32x4 acc[2][2] = {};
  for (int kt = 0; kt < 12; ++kt) {
    int k0 = kt*64;
    size_t ga = (size_t)(n0 + srow)*768 + k0 + sseg;
    size_t gw = (size_t)(m0 + srow)*768 + k0 + sseg;
    u16x8 va0 = *(const u16x8*)(Ah + ga); u16x8 va1 = *(const u16x8*)(Ah + ga + 8);
    u16x8 va2 = *(const u16x8*)(Al + ga); u16x8 va3 = *(const u16x8*)(Al + ga + 8);
    u16x8 vw0 = *(const u16x8*)(Wh + gw); u16x8 vw1 = *(const u16x8*)(Wh + gw + 8);
    u16x8 vw2 = *(const u16x8*)(Wl + gw); u16x8 vw3 = *(const u16x8*)(Wl + gw + 8);
    int lo = srow*ST + sseg;
    *(u16x8*)&Ash[lo] = va0; *(u16x8*)&Ash[lo + 8] = va1;
    *(u16x8*)&Asl[lo] = va2; *(u16x8*)&Asl[lo + 8] = va3;
    *(u16x8*)&Wsh[lo] = vw0; *(u16x8*)&Wsh[lo + 8] = vw1;
    *(u16x8*)&Wsl[lo] = vw2; *(u16x8*)&Wsl[lo + 8] = vw3;
    __syncthreads();
#pragma unroll
    for (int ks = 0; ks < 2; ++ks) {
      int co = ks*32 + lg*8;
      bf16x8 fah[2], fal[2], fwh[2], fwl[2];
#pragma unroll
      for (int i = 0; i < 2; ++i) {
        int ar = wr0 + 16*i + lr;
        fah[i] = *(const bf16x8*)&Ash[ar*ST + co];
        fal[i] = *(const bf16x8*)&Asl[ar*ST + co];
        int wr2 = wc0 + 16*i + lr;
        fwh[i] = *(const bf16x8*)&Wsh[wr2*ST + co];
        fwl[i] = *(const bf16x8*)&Wsl[wr2*ST + co];
      }
#pragma unroll
      for (int i = 0; i < 2; ++i)
#pragma unroll
        for (int j = 0; j < 2; ++j) {
          acc[i][j] = __builtin_amdgcn_mfma_f32_16x16x32_bf16(fah[i], fwh[j], acc[i][j], 0, 0, 0);
          acc[i][j] = __builtin_amdgcn_mfma_f32_16x16x32_bf16(fah[i], fwl[j], acc[i][j], 0, 0, 0);
          acc[i][j] = __builtin_amdgcn_mfma_f32_16x16x32_bf16(fal[i], fwh[j], acc[i][j], 0, 0, 0);
          acc[i][j] = __builtin_amdgcn_mfma_f32_16x16x32_bf16(fal[i], fwl[j], acc[i][j], 0, 0, 0);
        }
    }
    __syncthreads();
  }
#pragma unroll
  for (int i = 0; i < 2; ++i)
#pragma unroll
    for (int j = 0; j < 2; ++j) {
      int m = m0 + wc0 + 16*j + lr;
      float bvv = bias[m];
#pragma unroll
      for (int r = 0; r < 4; ++r) {
        int n = n0 + wr0 + 16*i + lg*4 + r;
        float val = (acc[i][j][r] + bvv) * scale;
        if (PATH == 1) {
          Oout[(size_t)n*D + m] = val;
        } else {
          int b = n >> 11, s = n & 2047, hh2 = m >> 6, dh2 = m & 63;
          size_t o = (((size_t)b*H + hh2)*S + s)*DH + dh2;
          if (z == 0) {
            ushort vh, vl; bf16_split(val, vh, vl);
            Qh[o] = vh; Ql[o] = vl;
          } else if (z == 1) {
            Kout[o] = val;
            if (b == 0) {
              ushort vh, vl; bf16_split(val, vh, vl);
              Kbh[o] = vh; Kbl[o] = vl;
            }
          } else {
            Vout[o] = val;
          }
        }
      }
    }
}

// ---------------------------------------------------------------------------
// Leverage stage A1: per-head partial KtK over 128-row chunks (batch 0 only)
// ---------------------------------------------------------------------------
__global__ __launch_bounds__(256) void levA1_kernel(
    const float* __restrict__ Kmat, float* __restrict__ partials) {
  int h = blockIdx.x, blk = blockIdx.y;
  __shared__ __align__(16) float ktile[128*64];
  int tid = threadIdx.x;
  const float* Kh = Kmat + ((size_t)h*S + (size_t)blk*128)*DH;
#pragma unroll
  for (int r = 0; r < 32; ++r) { int e = tid + 256*r; ktile[e] = Kh[e]; }
  __syncthreads();
  int j4 = tid & 15;
  float accf[4][4] = {};
  for (int ss = 0; ss < 128; ++ss) {
    float4 kj = ((const float4*)(ktile + ss*64))[j4];
#pragma unroll
    for (int r = 0; r < 4; ++r) {
      int i = (tid >> 4) + 16*r;
      float ki = ktile[ss*64 + i];
      accf[r][0] += ki*kj.x; accf[r][1] += ki*kj.y;
      accf[r][2] += ki*kj.z; accf[r][3] += ki*kj.w;
    }
  }
  size_t base = ((size_t)h*16 + blk)*4096;
#pragma unroll
  for (int r = 0; r < 4; ++r) {
    int i = (tid >> 4) + 16*r;
#pragma unroll
    for (int c = 0; c < 4; ++c)
      partials[base + (size_t)i*64 + j4*4 + c] = accf[r][c];
  }
}

// ---------------------------------------------------------------------------
// Leverage stage A0-reduce: fp64 sum of the 16 partials + damping.
// ---------------------------------------------------------------------------
__global__ __launch_bounds__(256) void levA0_kernel(
    const float* __restrict__ partials, float* __restrict__ KtK) {
  int g = blockIdx.x*256 + threadIdx.x;        // 0 .. H*4096-1
  int h = g >> 12, e = g & 4095;
  const float* pb = partials + (size_t)h*65536 + e;
  double t = 0.0;
#pragma unroll
  for (int p = 0; p < 16; ++p) t += (double)pb[(size_t)p*4096];
  if ((e >> 6) == (e & 63)) t += 1e-6;
  KtK[g] = (float)t;
}

// ---------------------------------------------------------------------------
// Newton-iteration inverse via MFMA. One block (256 thr, 4 waves) per head.
// X0 = I/||A||inf; 12 iters of X' = 2X - sym(X A X^T). X stays bitwise
// symmetric. Epilogue also emits bf16 hi/lo splits of inv for levB's MFMA.
// ---------------------------------------------------------------------------
__global__ __launch_bounds__(256) void newton_inv_kernel(
    const float* __restrict__ KtK, float* __restrict__ invOut,
    ushort* __restrict__ invH, ushort* __restrict__ invL) {
  const int SF = 68;
  const int SB = 72;
  __shared__ float Xf[64*SF];
  __shared__ float Uf[64*SF];
  __shared__ __align__(16) ushort Ah[64*SB], Al[64*SB];
  __shared__ __align__(16) ushort Xh[64*SB], Xl[64*SB];
  __shared__ __align__(16) ushort Th[64*SB], Tl[64*SB];
  __shared__ float rsum[64];
  __shared__ float csh;
  int h = blockIdx.x, tid = threadIdx.x;
  int w = tid >> 6, lane = tid & 63;
  int lr = lane & 15, lg = lane >> 4;
  int r = tid >> 2, qq = tid & 3;

  float s = 0.f;
  {
    const float* src = KtK + (size_t)h*4096 + (size_t)r*64 + qq*16;
#pragma unroll
    for (int i = 0; i < 16; ++i) {
      float a = src[i];
      s += fabsf(a);
      ushort hh, ll; bf16_split(a, hh, ll);
      Ah[r*SB + qq*16 + i] = hh; Al[r*SB + qq*16 + i] = ll;
    }
    s += __shfl_xor(s, 1);
    s += __shfl_xor(s, 2);
    if (qq == 0) rsum[r] = s;
  }
  __syncthreads();
  if (tid < 64) {
    float m = rsum[tid];
#pragma unroll
    for (int o = 32; o; o >>= 1) m = fmaxf(m, __shfl_xor(m, o));
    if (tid == 0) csh = 1.0f / m;
  }
  __syncthreads();
  float c = csh;
#pragma unroll
  for (int i = 0; i < 16; ++i) {
    int e = qq*16 + i;
    float x0 = (e == r) ? c : 0.0f;
    Xf[r*SF + e] = x0;
    ushort hh, ll; bf16_split(x0, hh, ll);
    Xh[r*SB + e] = hh; Xl[r*SB + e] = ll;
  }
  __syncthreads();

  int n0 = (w >> 1)*32, m0 = (w & 1)*32;
  for (int it = 0; it < 12; ++it) {
    // P1: T' = X * A^T
    {
      f32x4 acc[2][2] = {};
#pragma unroll
      for (int ks = 0; ks < 2; ++ks) {
        bf16x8 pah[2], pal[2], pbh[2], pbl[2];
#pragma unroll
        for (int i = 0; i < 2; ++i) {
          int ao = (n0 + 16*i + lr)*SB + ks*32 + lg*8;
          pah[i] = *(const bf16x8*)&Xh[ao]; pal[i] = *(const bf16x8*)&Xl[ao];
          int bo2 = (m0 + 16*i + lr)*SB + ks*32 + lg*8;
          pbh[i] = *(const bf16x8*)&Ah[bo2]; pbl[i] = *(const bf16x8*)&Al[bo2];
        }
#pragma unroll
        for (int i = 0; i < 2; ++i)
#pragma unroll
          for (int j = 0; j < 2; ++j) {
            acc[i][j] = __builtin_amdgcn_mfma_f32_16x16x32_bf16(pah[i], pbh[j], acc[i][j], 0, 0, 0);
            acc[i][j] = __builtin_amdgcn_mfma_f32_16x16x32_bf16(pah[i], pbl[j], acc[i][j], 0, 0, 0);
            acc[i][j] = __builtin_amdgcn_mfma_f32_16x16x32_bf16(pal[i], pbh[j], acc[i][j], 0, 0, 0);
            acc[i][j] = __builtin_amdgcn_mfma_f32_16x16x32_bf16(pal[i], pbl[j], acc[i][j], 0, 0, 0);
          }
      }
#pragma unroll
      for (int i = 0; i < 2; ++i)
#pragma unroll
        for (int j = 0; j < 2; ++j)
#pragma unroll
          for (int rr = 0; rr < 4; ++rr) {
            int n = n0 + 16*i + lg*4 + rr, m = m0 + 16*j + lr;
            ushort hh, ll; bf16_split(acc[i][j][rr], hh, ll);
            Th[n*SB + m] = hh; Tl[n*SB + m] = ll;
          }
    }
    __syncthreads();
    // P2: U = X * T'^T
    {
      f32x4 acc[2][2] = {};
#pragma unroll
      for (int ks = 0; ks < 2; ++ks) {
        bf16x8 pah[2], pal[2], pbh[2], pbl[2];
#pragma unroll
        for (int i = 0; i < 2; ++i) {
          int ao = (n0 + 16*i + lr)*SB + ks*32 + lg*8;
          pah[i] = *(const bf16x8*)&Xh[ao]; pal[i] = *(const bf16x8*)&Xl[ao];
          int bo2 = (m0 + 16*i + lr)*SB + ks*32 + lg*8;
          pbh[i] = *(const bf16x8*)&Th[bo2]; pbl[i] = *(const bf16x8*)&Tl[bo2];
        }
#pragma unroll
        for (int i = 0; i < 2; ++i)
#pragma unroll
          for (int j = 0; j < 2; ++j) {
            acc[i][j] = __builtin_amdgcn_mfma_f32_16x16x32_bf16(pah[i], pbh[j], acc[i][j], 0, 0, 0);
            acc[i][j] = __builtin_amdgcn_mfma_f32_16x16x32_bf16(pah[i], pbl[j], acc[i][j], 0, 0, 0);
            acc[i][j] = __builtin_amdgcn_mfma_f32_16x16x32_bf16(pal[i], pbh[j], acc[i][j], 0, 0, 0);
            acc[i][j] = __builtin_amdgcn_mfma_f32_16x16x32_bf16(pal[i], pbl[j], acc[i][j], 0, 0, 0);
          }
      }
#pragma unroll
      for (int i = 0; i < 2; ++i)
#pragma unroll
        for (int j = 0; j < 2; ++j)
#pragma unroll
          for (int rr = 0; rr < 4; ++rr) {
            int n = n0 + 16*i + lg*4 + rr, m = m0 + 16*j + lr;
            Uf[n*SF + m] = acc[i][j][rr];
          }
    }
    __syncthreads();
    // P3: X' = 2X - 0.5(U + U^T)
#pragma unroll
    for (int i = 0; i < 2; ++i)
#pragma unroll
      for (int j = 0; j < 2; ++j)
#pragma unroll
        for (int rr = 0; rr < 4; ++rr) {
          int n = n0 + 16*i + lg*4 + rr, m = m0 + 16*j + lr;
          float u = 0.5f*(Uf[n*SF + m] + Uf[m*SF + n]);
          float x = 2.0f*Xf[n*SF + m] - u;
          Xf[n*SF + m] = x;
          ushort hh, ll; bf16_split(x, hh, ll);
          Xh[n*SB + m] = hh; Xl[n*SB + m] = ll;
        }
    __syncthreads();
  }

#pragma unroll
  for (int i = 0; i < 16; ++i) {
    float x = Xf[r*SF + qq*16 + i];
    size_t o = (size_t)h*4096 + (size_t)r*64 + qq*16 + i;
    invOut[o] = x;
    ushort hh, ll; bf16_split(x, hh, ll);
    invH[o] = hh; invL[o] = ll;
  }
}

// ---------------------------------------------------------------------------
// Leverage stage B via MFMA: T = K @ inv (inv symmetric), lev = rowsum(T*K).
// ---------------------------------------------------------------------------
__global__ __launch_bounds__(256) void levB_kernel(
    const float* __restrict__ Kmat,
    const ushort* __restrict__ Kbh, const ushort* __restrict__ Kbl,
    const ushort* __restrict__ invH, const ushort* __restrict__ invL,
    float* __restrict__ lev) {
  int h = blockIdx.y;
  int tid = threadIdx.x;
  int w = tid >> 6, lane = tid & 63;
  int lr = lane & 15, lg = lane >> 4;
  int qbase = blockIdx.x*64 + w*16;
  f32x4 sacc[4] = {};
#pragma unroll
  for (int ks = 0; ks < 2; ++ks) {
    size_t ko = ((size_t)h*S + qbase + lr)*DH + ks*32 + lg*8;
    bf16x8 kh = *(const bf16x8*)(Kbh + ko);
    bf16x8 kl = *(const bf16x8*)(Kbl + ko);
#pragma unroll
    for (int f = 0; f < 4; ++f) {
      size_t io = (size_t)h*4096 + (size_t)(16*f + lr)*64 + ks*32 + lg*8;
      bf16x8 ih = *(const bf16x8*)(invH + io);
      bf16x8 il = *(const bf16x8*)(invL + io);
      sacc[f] = __builtin_amdgcn_mfma_f32_16x16x32_bf16(kh, ih, sacc[f], 0, 0, 0);
      sacc[f] = __builtin_amdgcn_mfma_f32_16x16x32_bf16(kh, il, sacc[f], 0, 0, 0);
      sacc[f] = __builtin_amdgcn_mfma_f32_16x16x32_bf16(kl, ih, sacc[f], 0, 0, 0);
      sacc[f] = __builtin_amdgcn_mfma_f32_16x16x32_bf16(kl, il, sacc[f], 0, 0, 0);
    }
  }
  float zc[4] = {};
#pragma unroll
  for (int f = 0; f < 4; ++f)
#pragma unroll
    for (int r = 0; r < 4; ++r) {
      float kv = Kmat[((size_t)h*S + qbase + lg*4 + r)*DH + 16*f + lr];
      zc[r] = fmaf(sacc[f][r], kv, zc[r]);
    }
#pragma unroll
  for (int r = 0; r < 4; ++r) {
    float t = zc[r];
    t += __shfl_xor(t, 1);
    t += __shfl_xor(t, 2);
    t += __shfl_xor(t, 4);
    t += __shfl_xor(t, 8);
    if (lr == 0) lev[(size_t)h*S + qbase + lg*4 + r] = t;
  }
}

// ---------------------------------------------------------------------------
// Top-k via bitonic sort (value desc, index asc)
// ---------------------------------------------------------------------------
__global__ __launch_bounds__(256) void topk_kernel(
    const float* __restrict__ lev, int* __restrict__ idx_list) {
  int h = blockIdx.x, tid = threadIdx.x;
  __shared__ float sv[2048];
  __shared__ int   si[2048];
#pragma unroll
  for (int r = 0; r < 8; ++r) {
    int e = tid + 256*r;
    sv[e] = lev[(size_t)h*S + e];
    si[e] = e;
  }
  __syncthreads();
  for (int k = 2; k <= 2048; k <<= 1) {
    for (int j = k >> 1; j > 0; j >>= 1) {
      for (int r = 0; r < 8; ++r) {
        int i = tid + 256*r;
        int l = i ^ j;
        if (l > i) {
          float v1 = sv[i], v2 = sv[l];
          int   i1 = si[i], i2 = si[l];
          bool before = (v1 > v2) || (v1 == v2 && i1 < i2);
          bool dir = ((i & k) == 0);
          if (before != dir) { sv[i]=v2; sv[l]=v1; si[i]=i2; si[l]=i1; }
        }
      }
      __syncthreads();
    }
  }
#pragma unroll
  for (int r = 0; r < 2; ++r) {
    int t = tid + 256*r;
    idx_list[h*TOPK + t] = si[t];
  }
}

// ---------------------------------------------------------------------------
// Gather kept K/V rows -> bf16 split buffers.
// KCh/KCl: [bh][512][64]; VCth/VCtl: [bh][64][512] (transposed)
// ---------------------------------------------------------------------------
__global__ __launch_bounds__(256) void gather_kernel(
    const float* __restrict__ Kmat, const float* __restrict__ Vmat,
    const int* __restrict__ idx_list,
    ushort* __restrict__ KCh, ushort* __restrict__ KCl,
    ushort* __restrict__ VCth, ushort* __restrict__ VCtl) {
  int bh = blockIdx.x;        // 0..23
  int kc = blockIdx.y;        // 0..7
  int h = bh % H;
  __shared__ float vt[64][65];
  int tid = threadIdx.x;
  int kk = tid >> 2;           // key within chunk (0..63)
  int dq = (tid & 3) * 16;     // dh base (0,16,32,48)
  int j = kc*64 + kk;
  int srow = idx_list[h*TOPK + j];
  const float* kr = Kmat + ((size_t)bh*S + srow)*DH + dq;
  const float* vr = Vmat + ((size_t)bh*S + srow)*DH + dq;
  ushort hh[16], ll[16];
#pragma unroll
  for (int i = 0; i < 16; ++i) bf16_split(kr[i], hh[i], ll[i]);
  size_t kbase = ((size_t)bh*TOPK + j)*DH + dq;
  *(u16x8*)(KCh + kbase)     = *(u16x8*)&hh[0];
  *(u16x8*)(KCh + kbase + 8) = *(u16x8*)&hh[8];
  *(u16x8*)(KCl + kbase)     = *(u16x8*)&ll[0];
  *(u16x8*)(KCl + kbase + 8) = *(u16x8*)&ll[8];
#pragma unroll
  for (int i = 0; i < 16; ++i) vt[kk][dq + i] = vr[i];
  __syncthreads();
  int d  = tid >> 2;           // dh row (0..63)
  int kq = (tid & 3) * 16;     // key base within chunk
#pragma unroll
  for (int i = 0; i < 16; ++i) bf16_split(vt[kq + i][d], hh[i], ll[i]);
  size_t vbase = ((size_t)bh*DH + d)*TOPK + kc*64 + kq;
  *(u16x8*)(VCth + vbase)     = *(u16x8*)&hh[0];
  *(u16x8*)(VCth + vbase + 8) = *(u16x8*)&hh[8];
  *(u16x8*)(VCtl + vbase)     = *(u16x8*)&ll[0];
  *(u16x8*)(VCtl + vbase + 8) = *(u16x8*)&ll[8];
}

// ---------------------------------------------------------------------------
// MFMA attention, split-bf16: LDS-staged K/V tiles, XCD-grouped swizzle.
// ---------------------------------------------------------------------------
__global__ __launch_bounds__(256) void attn_kernel(
    const ushort* __restrict__ Qh_g, const ushort* __restrict__ Ql_g,
    const ushort* __restrict__ KCh, const ushort* __restrict__ KCl,
    const ushort* __restrict__ VCth, const ushort* __restrict__ VCtl,
    ushort* __restrict__ CTXh, ushort* __restrict__ CTXl) {
  const int ST = 72;
  __shared__ __align__(16) ushort Kt_h[64*ST], Kt_l[64*ST];
  __shared__ __align__(16) ushort Vt_h[64*ST], Vt_l[64*ST];
  __shared__ __align__(16) ushort SQh[4][16][88];
  __shared__ __align__(16) ushort SQl[4][16][88];
  int tid = threadIdx.x;
  int w = tid >> 6;
  int lane = tid & 63;
  int lr = lane & 15, lg = lane >> 4;
  int bid = blockIdx.x;
  int xcd = bid & 7, jj = bid >> 3;
  int bh = xcd*3 + (jj >> 5);
  int qt = jj & 31;
  int qbase = qt*64 + w*16;
  int b = bh / H, h = bh % H;

  bf16x8 qh[2], ql[2];
#pragma unroll
  for (int ks = 0; ks < 2; ++ks) {
    size_t qo = ((size_t)bh*S + qbase + lr)*DH + ks*32 + lg*8;
    qh[ks] = *(const bf16x8*)(Qh_g + qo);
    ql[ks] = *(const bf16x8*)(Ql_g + qo);
  }

  f32x4 pacc[4] = {};
  float z_acc[4] = {};
  int srow = tid >> 2;
  int sseg = (tid & 3) * 16;

  for (int c = 0; c < 8; ++c) {
    int keybase = c*64;
    {
      size_t kg = ((size_t)bh*TOPK + keybase + srow)*DH + sseg;
      size_t vg = ((size_t)bh*DH + srow)*TOPK + keybase + sseg;
      u16x8 a0 = *(const u16x8*)(KCh + kg);
      u16x8 a1 = *(const u16x8*)(KCh + kg + 8);
      u16x8 b0 = *(const u16x8*)(KCl + kg);
      u16x8 b1 = *(const u16x8*)(KCl + kg + 8);
      u16x8 c0 = *(const u16x8*)(VCth + vg);
      u16x8 c1 = *(const u16x8*)(VCth + vg + 8);
      u16x8 d0 = *(const u16x8*)(VCtl + vg);
      u16x8 d1 = *(const u16x8*)(VCtl + vg + 8);
      int lo = srow*ST + sseg;
      *(u16x8*)&Kt_h[lo] = a0; *(u16x8*)&Kt_h[lo + 8] = a1;
      *(u16x8*)&Kt_l[lo] = b0; *(u16x8*)&Kt_l[lo + 8] = b1;
      *(u16x8*)&Vt_h[lo] = c0; *(u16x8*)&Vt_h[lo + 8] = c1;
      *(u16x8*)&Vt_l[lo] = d0; *(u16x8*)&Vt_l[lo + 8] = d1;
    }
    __syncthreads();
    f32x4 sacc[4] = {};
#pragma unroll
    for (int ks = 0; ks < 2; ++ks) {
#pragma unroll
      for (int f = 0; f < 4; ++f) {
        int ko = (16*f + lr)*ST + ks*32 + lg*8;
        bf16x8 kh = *(const bf16x8*)&Kt_h[ko];
        bf16x8 kl = *(const bf16x8*)&Kt_l[ko];
        sacc[f] = __builtin_amdgcn_mfma_f32_16x16x32_bf16(qh[ks], kh, sacc[f], 0, 0, 0);
        sacc[f] = __builtin_amdgcn_mfma_f32_16x16x32_bf16(qh[ks], kl, sacc[f], 0, 0, 0);
        sacc[f] = __builtin_amdgcn_mfma_f32_16x16x32_bf16(ql[ks], kh, sacc[f], 0, 0, 0);
      }
    }
    float zc[4] = {};
#pragma unroll
    for (int f = 0; f < 4; ++f) {
#pragma unroll
      for (int r = 0; r < 4; ++r) {
        float s = sacc[f][r];
        float sq = s*s;
        zc[r] += sq;
        ushort hh, lo2; bf16_split(sq, hh, lo2);
        SQh[w][lg*4 + r][16*f + lr] = hh;
        SQl[w][lg*4 + r][16*f + lr] = lo2;
      }
    }
#pragma unroll
    for (int r = 0; r < 4; ++r) {
      float t = zc[r];
      t += __shfl_xor(t, 1);
      t += __shfl_xor(t, 2);
      t += __shfl_xor(t, 4);
      t += __shfl_xor(t, 8);
      z_acc[r] += t;
    }
#pragma unroll
    for (int ks = 0; ks < 2; ++ks) {
      bf16x8 ah = *(const bf16x8*)&SQh[w][lr][ks*32 + lg*8];
      bf16x8 al = *(const bf16x8*)&SQl[w][lr][ks*32 + lg*8];
#pragma unroll
      for (int f = 0; f < 4; ++f) {
        int vo = (16*f + lr)*ST + ks*32 + lg*8;
        bf16x8 vh = *(const bf16x8*)&Vt_h[vo];
        bf16x8 vl = *(const bf16x8*)&Vt_l[vo];
        pacc[f] = __builtin_amdgcn_mfma_f32_16x16x32_bf16(ah, vh, pacc[f], 0, 0, 0);
        pacc[f] = __builtin_amdgcn_mfma_f32_16x16x32_bf16(ah, vl, pacc[f], 0, 0, 0);
        pacc[f] = __builtin_amdgcn_mfma_f32_16x16x32_bf16(al, vh, pacc[f], 0, 0, 0);
      }
    }
    __syncthreads();
  }

  float zi[4];
#pragma unroll
  for (int r = 0; r < 4; ++r) zi[r] = 1.0f / (z_acc[r] + 1e-12f);
#pragma unroll
  for (int f = 0; f < 4; ++f) {
#pragma unroll
    for (int r = 0; r < 4; ++r) {
      int q = lg*4 + r;
      float val = pacc[f][r] * zi[r];
      ushort hh, lo2; bf16_split(val, hh, lo2);
      size_t o = ((size_t)b*S + qbase + q)*D + h*DH + 16*f + lr;
      CTXh[o] = hh; CTXl[o] = lo2;
    }
  }
}

// ---------------------------------------------------------------------------
extern "C" void kernel_launch(void* const* d_in, const int* in_sizes, int n_in,
                              void* d_out, int out_size, void* d_ws, size_t ws_size,
                              hipStream_t stream) {
  const float* query = (const float*)d_in[0];
  const float* key   = (const float*)d_in[1];
  const float* value = (const float*)d_in[2];
  const float* Wq = (const float*)d_in[3];
  const float* bq = (const float*)d_in[4];
  const float* Wk = (const float*)d_in[5];
  const float* bk = (const float*)d_in[6];
  const float* Wv = (const float*)d_in[7];
  const float* bv = (const float*)d_in[8];
  const float* Wo = (const float*)d_in[9];
  const float* bo = (const float*)d_in[10];
  float* out = (float*)d_out;

  const size_t QKV = QKVSZ;
  const size_t WSZ = WSZC;
  const size_t KB0 = (size_t)H*S*DH;          // 1,572,864 (batch-0 K)
  ushort* X3h = (ushort*)d_ws;                // [3][QKV] input splits
  ushort* X3l = X3h + 3*QKV;
  ushort* Qh  = X3l + 3*QKV;
  ushort* Ql  = Qh + QKV;
  float*  Kws = (float*)(Ql + QKV);
  float*  Vws = Kws + QKV;
  float*  partials = Vws + QKV;               // 786,432
  float*  ktkWs = partials + (size_t)H*16*4096;
  float*  invWs = ktkWs + (size_t)H*4096;
  float*  levWs = invWs + (size_t)H*4096;
  ushort* Xh  = (ushort*)(levWs + (size_t)H*S);   // ctx split (attn out)
  ushort* Xl  = Xh + QKV;
  ushort* Wqh = Xl + QKV;                     // 8 contiguous W slabs
  ushort* KCh  = Wqh + 8*WSZ;
  ushort* KCl  = KCh  + (size_t)B*H*TOPK*DH;
  ushort* VCth = KCl  + (size_t)B*H*TOPK*DH;
  ushort* VCtl = VCth + (size_t)B*H*TOPK*DH;
  ushort* Kbh  = VCtl + (size_t)B*H*TOPK*DH;  // batch-0 K split
  ushort* Kbl  = Kbh + KB0;
  ushort* invH = Kbl + KB0;
  ushort* invL = invH + (size_t)H*4096;
  int*   idxWs = (int*)(invL + (size_t)H*4096);

  const int nW8 = (int)(WSZ/8), nX8 = (int)(QKV/8);
  splitw4_kernel<<<dim3(nW8/256, 1, 4), 256, 0, stream>>>(Wq, Wk, Wv, Wo, Wqh, nW8);
  split3_kernel<<<dim3(nX8/256, 1, 3), 256, 0, stream>>>(query, key, value, X3h, X3l, nX8);

  // batched QKV projection (z=0 Q, z=1 K, z=2 V)
  projmf2_kernel<0><<<dim3(NROW/64, D/64, 3), 256, 0, stream>>>(
      X3h, X3l, Wqh, bq, bk, bv, bo, Kws, Vws, Qh, Ql, Kbh, Kbl, nullptr);

  levA1_kernel<<<dim3(H,16), 256, 0, stream>>>(Kws, partials);
  levA0_kernel<<<(H*4096)/256, 256, 0, stream>>>(partials, ktkWs);
  newton_inv_kernel<<<H, 256, 0, stream>>>(ktkWs, invWs, invH, invL);
  levB_kernel<<<dim3(S/64, H), 256, 0, stream>>>(Kws, Kbh, Kbl, invH, invL, levWs);
  topk_kernel<<<H, 256, 0, stream>>>(levWs, idxWs);

  gather_kernel<<<dim3(B*H, TOPK/64), 256, 0, stream>>>(
      Kws, Vws, idxWs, KCh, KCl, VCth, VCtl);

  attn_kernel<<<B*H*(S/64), 256, 0, stream>>>(Qh, Ql, KCh, KCl, VCth, VCtl, Xh, Xl);

  // output projection (PATH 1, z=3 selects Wo)
  projmf2_kernel<1><<<dim3(NROW/64, D/64, 1), 256, 0, stream>>>(
      Xh, Xl, Wqh, bq, bk, bv, bo, nullptr, nullptr, nullptr, nullptr,
      nullptr, nullptr, out);
}